// Round 2
// baseline (1307.841 us; speedup 1.0000x reference)
//
#include <hip/hip_runtime.h>
#include <hip/hip_bf16.h>

#define B_    256
#define L_    512
#define DV    21
#define NROW  5376       // B_*DV
#define NP    32
#define PP    16
#define PRED_ 96

// ---------------- workspace layout (float indices) ----------------
static const size_t OFF_XT    = 0;          // 5376x512 f32
static const size_t OFF_ZA    = 2752512;    // z_dct -> z -> t -> z2 (aliased over time)
static const size_t OFF_Z1    = 5505024;
static const size_t OFF_ZCP   = 8257536;    // zc_pre -> z2f (in-place)
static const size_t OFF_D2    = 11010048;   // 512x512
static const size_t OFF_D3    = 11272192;
static const size_t OFF_M     = 11534336;   // 512x96 folded linres
static const size_t OFF_TN    = 11583488;   // 32x16x16
static const size_t OFF_TB    = 11591680;   // 32x16
static const size_t OFF_C     = 11592192;   // 96 (pad 128)
static const size_t OFF_EN    = 11592320;   // 5376
static const size_t OFF_NORM  = 11597696;
static const size_t OFF_ATT   = 11603072;
static const size_t OFF_ATT1  = 11608448;
static const size_t OFF_STAT  = 11613824;   // 256: [0..41]dct [42..105]patch [106..169]dep [170,171]att [200],[201]=thr order stats
static const size_t OFF_ABD   = 11614080;   // 64
static const size_t OFF_ABP   = 11614144;   // 64
static const size_t OFF_ABDEP = 11614208;   // 64
static const size_t OFF_FLAG  = 11614272;   // int mode flag (1=f32 inputs, 0=bf16)
static const size_t OFF_STG   = 11614336;   // staged f32 weights (854480)
// total 12468816 floats = 49.9 MB

// staged-weight offsets (relative to OFF_STG)
static const int S_WDCT=0, S_BDCT=24, S_WE=48, S_BE=4144, S_WL=4400, S_BL=790832,
  S_WD=790928, S_BDRES=795024, S_WDC=795040, S_BDC=795552, S_WDC1=795584, S_BDC1=795680,
  S_GD=795712, S_BDN=795736, S_GP=795760, S_BP=795792, S_GDEP=795824, S_BDEP=795856,
  S_THR=795888, S_WM1=795892, S_BM1=845044, S_WM2=845140, S_BM2=854356,
  S_ADWW=854452, S_ADWB=854460, S_ACW=854464, S_ACB=854468, S_AG=854472, S_AB2=854476;

struct Ptrs { const void* p[30]; };

__device__ __forceinline__ float bf2f(unsigned short h){
  unsigned u = ((unsigned)h) << 16;
  return __uint_as_float(u);
}
__device__ __forceinline__ float gelu_f(float x){ return 0.5f*x*(1.0f+erff(x*0.70710678118654752440f)); }

// ---------------- init: zero stats + detect input dtype ----------------
__global__ void k_init(const unsigned* __restrict__ gones, float* __restrict__ stat, int* __restrict__ flag){
  stat[threadIdx.x] = 0.0f;
  if (threadIdx.x == 0) *flag = (gones[0] == 0x3F800000u) ? 1 : 0;
}

// ---------------- stage all weights (inputs 1..29) to f32 ----------------
__global__ __launch_bounds__(256) void k_stage(Ptrs ptrs, float* __restrict__ dst, const int* __restrict__ flag){
  const int cnt[29] = {21,21,4096,256,786432,96,4096,16,512,32,96,32,21,21,32,32,32,32,1,49152,96,9216,96,5,1,1,1,1,1};
  const int off[29] = {S_WDCT,S_BDCT,S_WE,S_BE,S_WL,S_BL,S_WD,S_BDRES,S_WDC,S_BDC,S_WDC1,S_BDC1,
                       S_GD,S_BDN,S_GP,S_BP,S_GDEP,S_BDEP,S_THR,S_WM1,S_BM1,S_WM2,S_BM2,
                       S_ADWW,S_ADWB,S_ACW,S_ACB,S_AG,S_AB2};
  int mode = *flag;
  int gid = blockIdx.x*256 + threadIdx.x;
  int a = -1, loc = 0, base = 0;
  #pragma unroll
  for (int i = 0; i < 29; i++){
    if (a < 0 && gid < base + cnt[i]){ a = i; loc = gid - base; }
    base += cnt[i];
  }
  if (a < 0) return;
  const void* s = ptrs.p[a+1];
  float v = mode ? ((const float*)s)[loc] : bf2f(((const unsigned short*)s)[loc]);
  dst[off[a] + loc] = v;
}

// ---------------- transpose x (B,L,D) -> xt (B*D, L) f32, dual dtype ----------------
__global__ __launch_bounds__(256) void k_transpose(const void* __restrict__ x, float* __restrict__ xt,
                                                   const int* __restrict__ flag){
  __shared__ float xs[L_*DV];
  int mode = *flag;
  int b = blockIdx.x;
  if (mode){
    const float* xp = (const float*)x + (size_t)b*(L_*DV);
    for (int i = threadIdx.x; i < L_*DV; i += 256) xs[i] = xp[i];
  } else {
    const unsigned short* xp = (const unsigned short*)x + (size_t)b*(L_*DV);
    for (int i = threadIdx.x; i < L_*DV; i += 256) xs[i] = bf2f(xp[i]);
  }
  __syncthreads();
  float* op = xt + (size_t)b*(L_*DV);
  for (int i = threadIdx.x; i < L_*DV; i += 256){
    int l = i & 511, d = i >> 9;
    op[i] = xs[l*DV + d];
  }
}

// ---------------- DCT matrices (exact integer range reduction) ----------------
__global__ __launch_bounds__(256) void k_dctmats(float* __restrict__ D2, float* __restrict__ D3){
  int i = blockIdx.x*256 + threadIdx.x;
  int kk = i >> 9, m = i & 511;
  const float PIo = 3.14159265358979323846f / 1024.0f;
  int a = ((2*m+1)*kk) & 2047;
  D2[i] = 2.0f * cosf(PIo * (float)a);
  int l = kk, k = m;
  int a2 = ((2*l+1)*k) & 2047;
  float w0 = (k==0) ? 0.5f : 1.0f;
  D3[i] = cosf(PIo * (float)a2) * w0 * (1.0f/512.0f);
}

// ---------------- fold patch-branch weights (all staged f32) ----------------
__global__ __launch_bounds__(256) void k_foldmats(const float* __restrict__ S,
    float* __restrict__ M, float* __restrict__ c, float* __restrict__ Tn, float* __restrict__ tb){
  const float* We = S + S_WE;  const float* be = S + S_BE;
  const float* Wl = S + S_WL;  const float* bl = S + S_BL;
  const float* Wd = S + S_WD;  const float* bdres = S + S_BDRES;
  const float* wdc = S + S_WDC; const float* bdc = S + S_BDC;
  int blk = blockIdx.x, tid = threadIdx.x;
  if (blk < 192){
    int gid = blk*256 + tid;        // 49152 = 512*96
    int l = gid/96, p = gid - l*96;
    int n = l>>4, q = l&15;
    float acc = 0.f;
    for (int j=0;j<256;j++) acc += We[q*256+j] * Wl[(size_t)(n*256+j)*96 + p];
    M[(size_t)l*96+p] = acc;
  } else if (blk == 192){
    if (tid < 96){
      float acc = bl[tid];
      for (int n=0;n<32;n++)
        for (int j=0;j<256;j++) acc += be[j] * Wl[(size_t)(n*256+j)*96 + tid];
      c[tid] = acc;
    }
  } else {
    int n = blk - 193;              // 0..31
    int q2 = tid>>4, q = tid&15;    // q2 = patch pos, q = output
    float R = 0.f;
    for (int j=0;j<256;j++) R += We[q2*256+j] * Wd[j*16+q];
    float G = 0.f;
    for (int p=0;p<16;p++) G += We[q2*256 + q*16 + p] * wdc[n*16+p];
    Tn[n*256 + q2*16 + q] = R + G;
    if (tid < 16){
      float rb = bdres[tid];
      for (int j=0;j<256;j++) rb += be[j] * Wd[j*16+tid];
      float gb = bdc[n];
      for (int p=0;p<16;p++) gb += be[tid*16+p] * wdc[n*16+p];
      tb[n*16+tid] = rb + gb;
    }
  }
}

// ---------------- tiled f32 GEMM: C[r,col] = sum_m A'[r,m]*Bm[col*512+m] ----------------
// MODE 0: plain (dct).  MODE 1: A' = alpha_d*A+beta_d, epilogue += xt*w_dct+b_dct
template<int MODE>
__global__ __launch_bounds__(256) void k_gemm(
    const float* __restrict__ A, const float* __restrict__ Bm, float* __restrict__ C,
    const float* __restrict__ ab, const float* __restrict__ xt,
    const float* __restrict__ wdct, const float* __restrict__ bdct){
  __shared__ float As[16][65];
  __shared__ float Bs[16][65];
  int tid = threadIdx.x;
  int tx = tid & 15, ty = tid >> 4;
  int rowBase = blockIdx.y * 64;
  int colBase = blockIdx.x * 64;
  int lr = tid >> 2;
  int lk = (tid & 3) << 2;
  float alpha = 1.f, beta = 0.f;
  if (MODE == 1){ int d = (rowBase + lr) % DV; alpha = ab[2*d]; beta = ab[2*d+1]; }
  float acc[4][4] = {};
  for (int k0 = 0; k0 < 512; k0 += 16){
    float4 av = *(const float4*)(A + (size_t)(rowBase+lr)*512 + k0 + lk);
    if (MODE == 1){ av.x = alpha*av.x+beta; av.y = alpha*av.y+beta; av.z = alpha*av.z+beta; av.w = alpha*av.w+beta; }
    As[lk+0][lr] = av.x; As[lk+1][lr] = av.y; As[lk+2][lr] = av.z; As[lk+3][lr] = av.w;
    float4 bv = *(const float4*)(Bm + (size_t)(colBase+lr)*512 + k0 + lk);
    Bs[lk+0][lr] = bv.x; Bs[lk+1][lr] = bv.y; Bs[lk+2][lr] = bv.z; Bs[lk+3][lr] = bv.w;
    __syncthreads();
    #pragma unroll
    for (int kk = 0; kk < 16; kk++){
      float a0 = As[kk][ty*4+0], a1 = As[kk][ty*4+1], a2 = As[kk][ty*4+2], a3 = As[kk][ty*4+3];
      float b0 = Bs[kk][tx*4+0], b1 = Bs[kk][tx*4+1], b2 = Bs[kk][tx*4+2], b3 = Bs[kk][tx*4+3];
      acc[0][0] += a0*b0; acc[0][1] += a0*b1; acc[0][2] += a0*b2; acc[0][3] += a0*b3;
      acc[1][0] += a1*b0; acc[1][1] += a1*b1; acc[1][2] += a1*b2; acc[1][3] += a1*b3;
      acc[2][0] += a2*b0; acc[2][1] += a2*b1; acc[2][2] += a2*b2; acc[2][3] += a2*b3;
      acc[3][0] += a3*b0; acc[3][1] += a3*b1; acc[3][2] += a3*b2; acc[3][3] += a3*b3;
    }
    __syncthreads();
  }
  #pragma unroll
  for (int i = 0; i < 4; i++){
    int r = rowBase + ty*4 + i;
    #pragma unroll
    for (int j = 0; j < 4; j++){
      int cc = colBase + tx*4 + j;
      float v = acc[i][j];
      if (MODE == 1){
        int d = r % DV;
        v += xt[(size_t)r*512 + cc] * wdct[d] + bdct[d];
      }
      C[(size_t)r*512 + cc] = v;
    }
  }
}

// ---------------- energy per row ----------------
__global__ __launch_bounds__(256) void k_energy(const float* __restrict__ z, float* __restrict__ e){
  int tid = threadIdx.x;
  int r = blockIdx.x*4 + (tid>>6);
  int lane = tid & 63;
  const float* p = z + (size_t)r*512;
  float s = 0.f;
  #pragma unroll
  for (int w = 0; w < 8; w++){ float v = p[lane + w*64]; s += v*v; }
  for (int off = 32; off; off >>= 1) s += __shfl_down(s, off);
  if (lane == 0) e[r] = s;
}

// ---------------- median per batch row + norm_e ----------------
__global__ __launch_bounds__(256) void k_med(const float* __restrict__ e, float* __restrict__ norm){
  int b = threadIdx.x;
  float v[DV];
  for (int d = 0; d < DV; d++) v[d] = e[b*DV + d];
  float med = 0.f;
  for (int i = 0; i < DV; i++){
    int rk = 0;
    for (int j = 0; j < DV; j++) rk += (v[j] < v[i]) || (v[j] == v[i] && j < i);
    if (rk == 10) med = v[i];
  }
  float den = med + 1e-6f;
  for (int d = 0; d < DV; d++) norm[b*DV + d] = v[d] / den;
}

// ---------------- distributed rank-count quantile (order stats at i0,i0+1) ----------------
__global__ __launch_bounds__(256) void k_rank(const float* __restrict__ norm,
    const float* __restrict__ thrv, float* __restrict__ stat){
  int tid = threadIdx.x;
  int idx = blockIdx.x*64 + (tid >> 2);
  int qt = tid & 3;
  float val = norm[idx];
  int cnt = 0;
  int j0 = qt*1344;
  for (int j = j0; j < j0 + 1344; ++j){
    float v = norm[j];
    cnt += (v < val) || (v == val && j < idx);
  }
  __shared__ int sc[64][4];
  sc[tid>>2][qt] = cnt;
  __syncthreads();
  if (qt == 0){
    int rank = sc[tid>>2][0] + sc[tid>>2][1] + sc[tid>>2][2] + sc[tid>>2][3];
    float q = thrv[0];
    float pos = q * 5375.0f;
    int i0 = (int)floorf(pos);
    int i1 = (i0 + 1 > 5375) ? 5375 : i0 + 1;
    if (rank == i0) stat[200] = val;
    if (rank == i1) stat[201] = val;
  }
}

// ---------------- mask + scale + gelu + BN stats (in-place over zA) ----------------
__global__ __launch_bounds__(256) void k_maskgelu(float* __restrict__ zA, const float* __restrict__ norm,
    const float* __restrict__ stat, const float* __restrict__ thrv,
    const float* __restrict__ wdct, const float* __restrict__ bdct,
    float* __restrict__ dstats){
  int r = blockIdx.x, tid = threadIdx.x;
  int d = r % DV;
  float q = thrv[0];
  float pos = q * 5375.0f; float f = pos - floorf(pos);
  float thr = stat[200] + (stat[201] - stat[200]) * f;
  float mask = norm[r] > thr ? 1.0f : 0.0f;
  float w = wdct[d], b = bdct[d];
  float s = 0.f, s2 = 0.f;
  for (int i = tid; i < 512; i += 256){
    float v = zA[(size_t)r*512 + i] * mask * w + b;
    float g = gelu_f(v);
    zA[(size_t)r*512 + i] = g;
    s += g; s2 += g*g;
  }
  for (int off = 32; off; off >>= 1){ s += __shfl_down(s, off); s2 += __shfl_down(s2, off); }
  __shared__ float wsum[4][2];
  int wv = tid >> 6;
  if ((tid & 63) == 0){ wsum[wv][0] = s; wsum[wv][1] = s2; }
  __syncthreads();
  if (tid == 0){
    float S  = wsum[0][0]+wsum[1][0]+wsum[2][0]+wsum[3][0];
    float S2 = wsum[0][1]+wsum[1][1]+wsum[2][1]+wsum[3][1];
    atomicAdd(&dstats[2*d], S); atomicAdd(&dstats[2*d+1], S2);
  }
}

// ---------------- BN finalize: stats -> alpha,beta per channel ----------------
__global__ void k_bnfin(const float* __restrict__ stats, const float* __restrict__ g,
                        const float* __restrict__ b, int nchan, float count, float* __restrict__ ab){
  int c = threadIdx.x;
  if (c < nchan){
    float mean = stats[2*c] / count;
    float var  = stats[2*c+1] / count - mean*mean;
    float al = g[c] * rsqrtf(var + 1e-5f);
    float be = b[c] - mean * al;
    ab[2*c] = al; ab[2*c+1] = be;
  }
}

// ---------------- patch branch: t = zd+res via folded 16x16 matvecs (writes into zA) ----------------
__global__ __launch_bounds__(256) void k_patch(const float* __restrict__ xt, const float* __restrict__ Tn,
    const float* __restrict__ tb, float* __restrict__ t, float* __restrict__ pstats){
  __shared__ float xs[512];
  __shared__ float ssum[32], ssq[32];
  int r = blockIdx.x, tid = threadIdx.x;
  xs[tid]       = xt[(size_t)r*512 + tid];
  xs[tid + 256] = xt[(size_t)r*512 + tid + 256];
  if (tid < 32){ ssum[tid] = 0.f; ssq[tid] = 0.f; }
  __syncthreads();
  #pragma unroll
  for (int it = 0; it < 2; ++it){
    int idx = tid + it*256;
    int n = idx >> 4, qq = idx & 15;
    float acc = tb[n*16 + qq];
    #pragma unroll
    for (int q2 = 0; q2 < 16; q2++) acc += xs[n*16 + q2] * Tn[n*256 + q2*16 + qq];
    t[(size_t)r*512 + idx] = acc;
    atomicAdd(&ssum[n], acc); atomicAdd(&ssq[n], acc*acc);
  }
  __syncthreads();
  if (tid < 32){ atomicAdd(&pstats[2*tid], ssum[tid]); atomicAdd(&pstats[2*tid+1], ssq[tid]); }
}

// ---------------- z2 = gelu(bn(t)) [in-place over t]; zc_pre = conv3(z2); stats ----------------
__global__ __launch_bounds__(256) void k_z2(float* __restrict__ t, float* __restrict__ zcp,
    const float* __restrict__ abp, const float* __restrict__ wdc1,
    const float* __restrict__ bdc1, float* __restrict__ depstats){
  __shared__ float zs[512];
  __shared__ float ssum[32], ssq[32];
  int r = blockIdx.x, tid = threadIdx.x;
  if (tid < 32){ ssum[tid] = 0.f; ssq[tid] = 0.f; }
  for (int it = 0; it < 2; ++it){
    int idx = tid + it*256;
    int n = idx >> 4;
    float v = t[(size_t)r*512 + idx];
    zs[idx] = gelu_f(abp[2*n]*v + abp[2*n+1]);
  }
  __syncthreads();
  for (int it = 0; it < 2; ++it){
    int idx = tid + it*256;
    int n = idx >> 4, qq = idx & 15;
    float w0 = wdc1[n*3+0], w1 = wdc1[n*3+1], w2 = wdc1[n*3+2];
    float left  = qq > 0  ? zs[idx-1] : 0.f;
    float right = qq < 15 ? zs[idx+1] : 0.f;
    float cv = w0*left + w1*zs[idx] + w2*right + bdc1[n];
    zcp[(size_t)r*512 + idx] = cv;
    t[(size_t)r*512 + idx] = zs[idx];     // z2 overwrites t
    atomicAdd(&ssum[n], cv); atomicAdd(&ssq[n], cv*cv);
  }
  __syncthreads();
  if (tid < 32){ atomicAdd(&depstats[2*tid], ssum[tid]); atomicAdd(&depstats[2*tid+1], ssq[tid]); }
}

// ---------------- z2f = gelu(bn(zcp)) + z2  (in-place over zcp) ----------------
__global__ __launch_bounds__(256) void k_z2f(float* __restrict__ zcp, const float* __restrict__ z2,
    const float* __restrict__ ab){
  int idx = blockIdx.x*256 + threadIdx.x;
  int n = (idx >> 4) & 31;
  zcp[idx] = gelu_f(ab[2*n]*zcp[idx] + ab[2*n+1]) + z2[idx];
}

// ---------------- attention scalar per row ----------------
__global__ __launch_bounds__(256) void k_att(const float* __restrict__ z1, const float* __restrict__ z2f,
    const float* __restrict__ D2, const float* __restrict__ adww,
    const float* __restrict__ adwb, float* __restrict__ att, float* __restrict__ astats){
  int r = blockIdx.x, tid = threadIdx.x;
  float acc[5] = {};
  for (int it = 0; it < 2; ++it){
    int m = tid + it*256;
    float p = z1[(size_t)r*512 + m] * z2f[(size_t)r*512 + m];
    #pragma unroll
    for (int kf = 0; kf < 5; kf++) acc[kf] += p * D2[kf*512 + m];
  }
  for (int off = 32; off; off >>= 1){
    #pragma unroll
    for (int kf = 0; kf < 5; kf++) acc[kf] += __shfl_down(acc[kf], off);
  }
  __shared__ float wsum[4][5];
  if ((tid & 63) == 0){ for (int kf = 0; kf < 5; kf++) wsum[tid>>6][kf] = acc[kf]; }
  __syncthreads();
  if (tid == 0){
    const float rs = 22.627416997969522f;   // sqrt(512)
    float a = adwb[0];
    for (int kf = 0; kf < 5; kf++){
      float low = wsum[0][kf]+wsum[1][kf]+wsum[2][kf]+wsum[3][kf];
      float so = (kf == 0) ? 0.5f/rs : 0.70710678118654752440f/rs;
      a += low * so * adww[kf];
    }
    att[r] = a;
    atomicAdd(&astats[0], a); atomicAdd(&astats[1], a*a);
  }
}

// ---------------- att BN + gelu + softmax over d ----------------
__global__ __launch_bounds__(256) void k_attfin(const float* __restrict__ att, const float* __restrict__ astats,
    const float* __restrict__ ag, const float* __restrict__ abb,
    const float* __restrict__ acw, const float* __restrict__ acb,
    float* __restrict__ att1){
  int b = threadIdx.x;
  float mean = astats[0] / 5376.0f;
  float var  = astats[1] / 5376.0f - mean*mean;
  float al = ag[0] * rsqrtf(var + 1e-5f);
  float bb = abb[0];
  float cw = acw[0], cb2 = acb[0];
  float v[DV]; float mx = -1e30f;
  for (int d = 0; d < DV; d++){
    float a = att[b*DV + d];
    a = gelu_f(al*(a - mean) + bb);
    a = a*cw + cb2;
    v[d] = a; mx = fmaxf(mx, a);
  }
  float s = 0.f;
  for (int d = 0; d < DV; d++){ v[d] = expf(v[d] - mx); s += v[d]; }
  float inv = 1.0f / s;
  for (int d = 0; d < DV; d++) att1[b*DV + d] = v[d] * inv;
}

// ---------------- fused zsum -> MLP -> + z_res -> out (dual dtype) ----------------
__global__ __launch_bounds__(128) void k_mlp(const float* __restrict__ z1, const float* __restrict__ z2f,
    const float* __restrict__ att1, const float* __restrict__ xt, const float* __restrict__ M,
    const float* __restrict__ c, const float* __restrict__ S,
    void* __restrict__ outv, const int* __restrict__ flag){
  const float* Wm1 = S + S_WM1; const float* bm1 = S + S_BM1;
  const float* Wm2 = S + S_WM2; const float* bm2 = S + S_BM2;
  __shared__ float zs[512], xs[512], hs[96];
  int r = blockIdx.x, tid = threadIdx.x;
  int b = r / DV, d = r - b*DV;
  float a1 = att1[r];
  for (int i = tid; i < 512; i += 128){
    zs[i] = z1[(size_t)r*512 + i]*a1 + z2f[(size_t)r*512 + i]*(1.0f - a1);
    xs[i] = xt[(size_t)r*512 + i];
  }
  __syncthreads();
  if (tid < 96){
    float h = bm1[tid];
    for (int m = 0; m < 512; m++) h += zs[m] * Wm1[m*96 + tid];
    hs[tid] = gelu_f(h);
  }
  __syncthreads();
  if (tid < 96){
    float o = bm2[tid];
    for (int j = 0; j < 96; j++) o += hs[j] * Wm2[j*96 + tid];
    float zr = c[tid];
    for (int l = 0; l < 512; l++) zr += xs[l] * M[l*96 + tid];
    size_t oi = ((size_t)b*96 + tid)*DV + d;
    float val = zr + o;
    if (*flag) ((float*)outv)[oi] = val;
    else ((__hip_bfloat16*)outv)[oi] = __float2bfloat16(val);
  }
}

extern "C" void kernel_launch(void* const* d_in, const int* in_sizes, int n_in,
                              void* d_out, int out_size, void* d_ws, size_t ws_size,
                              hipStream_t stream) {
  float* w = (float*)d_ws;
  float* xt   = w + OFF_XT;
  float* zA   = w + OFF_ZA;
  float* z1   = w + OFF_Z1;
  float* zcp  = w + OFF_ZCP;
  float* D2   = w + OFF_D2;
  float* D3   = w + OFF_D3;
  float* Mb   = w + OFF_M;
  float* Tn   = w + OFF_TN;
  float* tb   = w + OFF_TB;
  float* cb   = w + OFF_C;
  float* en   = w + OFF_EN;
  float* nrm  = w + OFF_NORM;
  float* att  = w + OFF_ATT;
  float* att1 = w + OFF_ATT1;
  float* stat = w + OFF_STAT;
  float* abd  = w + OFF_ABD;
  float* abp  = w + OFF_ABP;
  float* abdep= w + OFF_ABDEP;
  int*   flag = (int*)(w + OFF_FLAG);
  float* S    = w + OFF_STG;

  Ptrs ptrs;
  for (int i = 0; i < 30; i++) ptrs.p[i] = d_in[i];

  k_init<<<1, 256, 0, stream>>>((const unsigned*)d_in[13], stat, flag);
  k_stage<<<3338, 256, 0, stream>>>(ptrs, S, flag);
  k_transpose<<<B_, 256, 0, stream>>>(d_in[0], xt, flag);
  k_dctmats<<<1024, 256, 0, stream>>>(D2, D3);
  k_foldmats<<<225, 256, 0, stream>>>(S, Mb, cb, Tn, tb);

  k_gemm<0><<<dim3(8,84), 256, 0, stream>>>(xt, D2, zA, abd, xt, S+S_WDCT, S+S_BDCT);
  k_energy<<<NROW/4, 256, 0, stream>>>(zA, en);
  k_med<<<1, 256, 0, stream>>>(en, nrm);
  k_rank<<<84, 256, 0, stream>>>(nrm, S+S_THR, stat);
  k_maskgelu<<<NROW, 256, 0, stream>>>(zA, nrm, stat, S+S_THR, S+S_WDCT, S+S_BDCT, stat + 0);
  k_bnfin<<<1, 64, 0, stream>>>(stat + 0, S+S_GD, S+S_BDN, DV, 131072.0f, abd);
  k_gemm<1><<<dim3(8,84), 256, 0, stream>>>(zA, D3, z1, abd, xt, S+S_WDCT, S+S_BDCT);

  k_patch<<<NROW, 256, 0, stream>>>(xt, Tn, tb, zA, stat + 42);
  k_bnfin<<<1, 64, 0, stream>>>(stat + 42, S+S_GP, S+S_BP, NP, 86016.0f, abp);
  k_z2<<<NROW, 256, 0, stream>>>(zA, zcp, abp, S+S_WDC1, S+S_BDC1, stat + 106);
  k_bnfin<<<1, 64, 0, stream>>>(stat + 106, S+S_GDEP, S+S_BDEP, NP, 86016.0f, abdep);
  k_z2f<<<NROW*2, 256, 0, stream>>>(zcp, zA, abdep);

  k_att<<<NROW, 256, 0, stream>>>(z1, zcp, D2, S+S_ADWW, S+S_ADWB, att, stat + 170);
  k_attfin<<<1, 256, 0, stream>>>(att, stat + 170, S+S_AG, S+S_AB2, S+S_ACW, S+S_ACB, att1);
  k_mlp<<<NROW, 128, 0, stream>>>(z1, zcp, att1, xt, Mb, cb, S, d_out, flag);
}

// Round 3
// 856.846 us; speedup vs baseline: 1.5263x; 1.5263x over previous
//
#include <hip/hip_runtime.h>
#include <hip/hip_bf16.h>

#define B_    256
#define L_    512
#define DV    21
#define NROW  5376       // B_*DV
#define NP    32
#define PP    16
#define PRED_ 96

// ---------------- workspace layout (float indices) ----------------
static const size_t OFF_XT    = 0;          // 5376x512 f32
static const size_t OFF_ZA    = 2752512;    // z_dct -> z -> t -> z2 -> Hcat/BcatT (aliased over time)
static const size_t OFF_Z1    = 5505024;
static const size_t OFF_ZCP   = 8257536;    // zc_pre -> z2f (in-place)
static const size_t OFF_D2    = 11010048;   // 512x512
static const size_t OFF_D3    = 11272192;
static const size_t OFF_M     = 11534336;   // 512x96 folded linres
static const size_t OFF_TN    = 11583488;   // 32x16x16
static const size_t OFF_TB    = 11591680;   // 32x16
static const size_t OFF_C     = 11592192;   // 96 (pad 128)
static const size_t OFF_EN    = 11592320;   // 5376
static const size_t OFF_NORM  = 11597696;
static const size_t OFF_ATT   = 11603072;
static const size_t OFF_ATT1  = 11608448;
static const size_t OFF_STAT  = 11613824;   // 256: [0..41]dct [42..105]patch [106..169]dep [170,171]att [200],[201]=thr order stats
static const size_t OFF_ABD   = 11614080;   // 64
static const size_t OFF_ABP   = 11614144;   // 64
static const size_t OFF_ABDEP = 11614208;   // 64
static const size_t OFF_FLAG  = 11614272;   // int mode flag (1=f32 inputs, 0=bf16)
static const size_t OFF_STG   = 11614336;   // staged f32 weights (854480)
// total 12468816 floats = 49.9 MB
// aliases inside OFF_ZA region (live only after z2f):
//   Hcat  = OFF_ZA            (5376 x 256)
//   BcatT = OFF_ZA + 1500000  (256 x 512)

// staged-weight offsets (relative to OFF_STG)
static const int S_WDCT=0, S_BDCT=24, S_WE=48, S_BE=4144, S_WL=4400, S_BL=790832,
  S_WD=790928, S_BDRES=795024, S_WDC=795040, S_BDC=795552, S_WDC1=795584, S_BDC1=795680,
  S_GD=795712, S_BDN=795736, S_GP=795760, S_BP=795792, S_GDEP=795824, S_BDEP=795856,
  S_THR=795888, S_WM1=795892, S_BM1=845044, S_WM2=845140, S_BM2=854356,
  S_ADWW=854452, S_ADWB=854460, S_ACW=854464, S_ACB=854468, S_AG=854472, S_AB2=854476;

struct Ptrs { const void* p[30]; };

__device__ __forceinline__ float bf2f(unsigned short h){
  unsigned u = ((unsigned)h) << 16;
  return __uint_as_float(u);
}
__device__ __forceinline__ float gelu_f(float x){ return 0.5f*x*(1.0f+erff(x*0.70710678118654752440f)); }

// ---------------- init: zero stats + c accum + detect input dtype ----------------
__global__ void k_init(const unsigned* __restrict__ gones, float* __restrict__ stat,
                       float* __restrict__ c, int* __restrict__ flag){
  stat[threadIdx.x] = 0.0f;
  if (threadIdx.x < 128) c[threadIdx.x] = 0.0f;
  if (threadIdx.x == 0) *flag = (gones[0] == 0x3F800000u) ? 1 : 0;
}

// ---------------- stage all weights (inputs 1..29) to f32 ----------------
__global__ __launch_bounds__(256) void k_stage(Ptrs ptrs, float* __restrict__ dst, const int* __restrict__ flag){
  const int cnt[29] = {21,21,4096,256,786432,96,4096,16,512,32,96,32,21,21,32,32,32,32,1,49152,96,9216,96,5,1,1,1,1,1};
  const int off[29] = {S_WDCT,S_BDCT,S_WE,S_BE,S_WL,S_BL,S_WD,S_BDRES,S_WDC,S_BDC,S_WDC1,S_BDC1,
                       S_GD,S_BDN,S_GP,S_BP,S_GDEP,S_BDEP,S_THR,S_WM1,S_BM1,S_WM2,S_BM2,
                       S_ADWW,S_ADWB,S_ACW,S_ACB,S_AG,S_AB2};
  int mode = *flag;
  int gid = blockIdx.x*256 + threadIdx.x;
  int a = -1, loc = 0, base = 0;
  #pragma unroll
  for (int i = 0; i < 29; i++){
    if (a < 0 && gid < base + cnt[i]){ a = i; loc = gid - base; }
    base += cnt[i];
  }
  if (a < 0) return;
  const void* s = ptrs.p[a+1];
  float v = mode ? ((const float*)s)[loc] : bf2f(((const unsigned short*)s)[loc]);
  dst[off[a] + loc] = v;
}

// ---------------- transpose x (B,L,D) -> xt (B*D, L) f32, dual dtype ----------------
__global__ __launch_bounds__(256) void k_transpose(const void* __restrict__ x, float* __restrict__ xt,
                                                   const int* __restrict__ flag){
  __shared__ float xs[L_*DV];
  int mode = *flag;
  int b = blockIdx.x;
  if (mode){
    const float* xp = (const float*)x + (size_t)b*(L_*DV);
    for (int i = threadIdx.x; i < L_*DV; i += 256) xs[i] = xp[i];
  } else {
    const unsigned short* xp = (const unsigned short*)x + (size_t)b*(L_*DV);
    for (int i = threadIdx.x; i < L_*DV; i += 256) xs[i] = bf2f(xp[i]);
  }
  __syncthreads();
  float* op = xt + (size_t)b*(L_*DV);
  for (int i = threadIdx.x; i < L_*DV; i += 256){
    int l = i & 511, d = i >> 9;
    op[i] = xs[l*DV + d];
  }
}

// ---------------- DCT matrices (exact integer range reduction) ----------------
__global__ __launch_bounds__(256) void k_dctmats(float* __restrict__ D2, float* __restrict__ D3){
  int i = blockIdx.x*256 + threadIdx.x;
  int kk = i >> 9, m = i & 511;
  const float PIo = 3.14159265358979323846f / 1024.0f;
  int a = ((2*m+1)*kk) & 2047;
  D2[i] = 2.0f * cosf(PIo * (float)a);
  int l = kk, k = m;
  int a2 = ((2*l+1)*k) & 2047;
  float w0 = (k==0) ? 0.5f : 1.0f;
  D3[i] = cosf(PIo * (float)a2) * w0 * (1.0f/512.0f);
}

// ---------------- fold patch-branch weights (all staged f32) ----------------
// blocks 0..191: M   blocks 192..199: c partials (atomic)   blocks 200..231: Tn/tb
__global__ __launch_bounds__(256) void k_foldmats(const float* __restrict__ S,
    float* __restrict__ M, float* __restrict__ c, float* __restrict__ Tn, float* __restrict__ tb){
  const float* We = S + S_WE;  const float* be = S + S_BE;
  const float* Wl = S + S_WL;  const float* bl = S + S_BL;
  const float* Wd = S + S_WD;  const float* bdres = S + S_BDRES;
  const float* wdc = S + S_WDC; const float* bdc = S + S_BDC;
  int blk = blockIdx.x, tid = threadIdx.x;
  if (blk < 192){
    int gid = blk*256 + tid;        // 49152 = 512*96
    int l = gid/96, p = gid - l*96;
    int n = l>>4, q = l&15;
    float acc = 0.f;
    for (int j=0;j<256;j++) acc += We[q*256+j] * Wl[(size_t)(n*256+j)*96 + p];
    M[(size_t)l*96+p] = acc;
  } else if (blk < 200){
    if (tid < 96){
      int J0 = (blk-192)*1024;
      float acc = (blk == 192) ? bl[tid] : 0.0f;
      for (int J = J0; J < J0+1024; J++) acc += be[J & 255] * Wl[(size_t)J*96 + tid];
      atomicAdd(&c[tid], acc);
    }
  } else {
    int n = blk - 200;              // 0..31
    int q2 = tid>>4, q = tid&15;    // q2 = patch pos, q = output
    float R = 0.f;
    for (int j=0;j<256;j++) R += We[q2*256+j] * Wd[j*16+q];
    float G = 0.f;
    for (int p=0;p<16;p++) G += We[q2*256 + q*16 + p] * wdc[n*16+p];
    Tn[n*256 + q2*16 + q] = R + G;
    if (tid < 16){
      float rb = bdres[tid];
      for (int j=0;j<256;j++) rb += be[j] * Wd[j*16+tid];
      float gb = bdc[n];
      for (int p=0;p<16;p++) gb += be[tid*16+p] * wdc[n*16+p];
      tb[n*16+tid] = rb + gb;
    }
  }
}

// ---------------- tiled f32 GEMM: C[r,col] = sum_m A'[r,m]*Bm[col*512+m] ----------------
// MODE 0: plain.  MODE 1: A' = alpha_d*A+beta_d, epilogue += xt*w_dct+b_dct.
// MODE 3: blockIdx.x<2 -> A' = att*A + (1-att)*A2 ; else A' = xt.  (MLP/zres fused GEMM)
template<int MODE>
__global__ __launch_bounds__(256) void k_gemm(
    const float* __restrict__ A, const float* __restrict__ A2,
    const float* __restrict__ Bm, float* __restrict__ C,
    const float* __restrict__ ab, const float* __restrict__ xt,
    const float* __restrict__ wdct, const float* __restrict__ bdct, int Cstride){
  __shared__ float As[16][68];   // pad 68 keeps 16B alignment for float4 reads
  __shared__ float Bs[16][68];
  int tid = threadIdx.x;
  int tx = tid & 15, ty = tid >> 4;
  int rowBase = blockIdx.y * 64;
  int colBase = blockIdx.x * 64;
  int lr = tid >> 2;
  int lk = (tid & 3) << 2;
  float alpha = 1.f, beta = 0.f;
  bool mixA = false;
  if (MODE == 1){ int d = (rowBase + lr) % DV; alpha = ab[2*d]; beta = ab[2*d+1]; }
  if (MODE == 3){ mixA = (blockIdx.x < 2); if (mixA) alpha = ab[rowBase + lr]; }
  float acc[4][4] = {};
  for (int k0 = 0; k0 < 512; k0 += 16){
    float4 av;
    if (MODE == 3 && !mixA) av = *(const float4*)(xt + (size_t)(rowBase+lr)*512 + k0 + lk);
    else                    av = *(const float4*)(A  + (size_t)(rowBase+lr)*512 + k0 + lk);
    if (MODE == 1){ av.x = alpha*av.x+beta; av.y = alpha*av.y+beta; av.z = alpha*av.z+beta; av.w = alpha*av.w+beta; }
    if (MODE == 3 && mixA){
      float4 a2 = *(const float4*)(A2 + (size_t)(rowBase+lr)*512 + k0 + lk);
      float om = 1.0f - alpha;
      av.x = alpha*av.x + om*a2.x; av.y = alpha*av.y + om*a2.y;
      av.z = alpha*av.z + om*a2.z; av.w = alpha*av.w + om*a2.w;
    }
    As[lk+0][lr] = av.x; As[lk+1][lr] = av.y; As[lk+2][lr] = av.z; As[lk+3][lr] = av.w;
    float4 bv = *(const float4*)(Bm + (size_t)(colBase+lr)*512 + k0 + lk);
    Bs[lk+0][lr] = bv.x; Bs[lk+1][lr] = bv.y; Bs[lk+2][lr] = bv.z; Bs[lk+3][lr] = bv.w;
    __syncthreads();
    #pragma unroll
    for (int kk = 0; kk < 16; kk++){
      float4 a4 = *(const float4*)&As[kk][ty*4];
      float4 b4 = *(const float4*)&Bs[kk][tx*4];
      acc[0][0] += a4.x*b4.x; acc[0][1] += a4.x*b4.y; acc[0][2] += a4.x*b4.z; acc[0][3] += a4.x*b4.w;
      acc[1][0] += a4.y*b4.x; acc[1][1] += a4.y*b4.y; acc[1][2] += a4.y*b4.z; acc[1][3] += a4.y*b4.w;
      acc[2][0] += a4.z*b4.x; acc[2][1] += a4.z*b4.y; acc[2][2] += a4.z*b4.z; acc[2][3] += a4.z*b4.w;
      acc[3][0] += a4.w*b4.x; acc[3][1] += a4.w*b4.y; acc[3][2] += a4.w*b4.z; acc[3][3] += a4.w*b4.w;
    }
    __syncthreads();
  }
  #pragma unroll
  for (int i = 0; i < 4; i++){
    int r = rowBase + ty*4 + i;
    #pragma unroll
    for (int j = 0; j < 4; j++){
      int cc = colBase + tx*4 + j;
      float v = acc[i][j];
      if (MODE == 1){
        int d = r % DV;
        v += xt[(size_t)r*512 + cc] * wdct[d] + bdct[d];
      }
      C[(size_t)r*Cstride + cc] = v;
    }
  }
}

// ---------------- energy per row ----------------
__global__ __launch_bounds__(256) void k_energy(const float* __restrict__ z, float* __restrict__ e){
  int tid = threadIdx.x;
  int r = blockIdx.x*4 + (tid>>6);
  int lane = tid & 63;
  const float* p = z + (size_t)r*512;
  float s = 0.f;
  #pragma unroll
  for (int w = 0; w < 8; w++){ float v = p[lane + w*64]; s += v*v; }
  for (int off = 32; off; off >>= 1) s += __shfl_down(s, off);
  if (lane == 0) e[r] = s;
}

// ---------------- median per batch row + norm_e ----------------
__global__ __launch_bounds__(256) void k_med(const float* __restrict__ e, float* __restrict__ norm){
  int b = threadIdx.x;
  float v[DV];
  for (int d = 0; d < DV; d++) v[d] = e[b*DV + d];
  float med = 0.f;
  for (int i = 0; i < DV; i++){
    int rk = 0;
    for (int j = 0; j < DV; j++) rk += (v[j] < v[i]) || (v[j] == v[i] && j < i);
    if (rk == 10) med = v[i];
  }
  float den = med + 1e-6f;
  for (int d = 0; d < DV; d++) norm[b*DV + d] = v[d] / den;
}

// ---------------- distributed rank-count quantile (order stats at i0,i0+1) ----------------
__global__ __launch_bounds__(256) void k_rank(const float* __restrict__ norm,
    const float* __restrict__ thrv, float* __restrict__ stat){
  int tid = threadIdx.x;
  int idx = blockIdx.x*64 + (tid >> 2);
  int qt = tid & 3;
  float val = norm[idx];
  int cnt = 0;
  int j0 = qt*1344;
  for (int j = j0; j < j0 + 1344; ++j){
    float v = norm[j];
    cnt += (v < val) || (v == val && j < idx);
  }
  __shared__ int sc[64][4];
  sc[tid>>2][qt] = cnt;
  __syncthreads();
  if (qt == 0){
    int rank = sc[tid>>2][0] + sc[tid>>2][1] + sc[tid>>2][2] + sc[tid>>2][3];
    float q = thrv[0];
    float pos = q * 5375.0f;
    int i0 = (int)floorf(pos);
    int i1 = (i0 + 1 > 5375) ? 5375 : i0 + 1;
    if (rank == i0) stat[200] = val;
    if (rank == i1) stat[201] = val;
  }
}

// ---------------- mask + scale + gelu + BN stats (in-place over zA) ----------------
__global__ __launch_bounds__(256) void k_maskgelu(float* __restrict__ zA, const float* __restrict__ norm,
    const float* __restrict__ stat, const float* __restrict__ thrv,
    const float* __restrict__ wdct, const float* __restrict__ bdct,
    float* __restrict__ dstats){
  int r = blockIdx.x, tid = threadIdx.x;
  int d = r % DV;
  float q = thrv[0];
  float pos = q * 5375.0f; float f = pos - floorf(pos);
  float thr = stat[200] + (stat[201] - stat[200]) * f;
  float mask = norm[r] > thr ? 1.0f : 0.0f;
  float w = wdct[d], b = bdct[d];
  float s = 0.f, s2 = 0.f;
  for (int i = tid; i < 512; i += 256){
    float v = zA[(size_t)r*512 + i] * mask * w + b;
    float g = gelu_f(v);
    zA[(size_t)r*512 + i] = g;
    s += g; s2 += g*g;
  }
  for (int off = 32; off; off >>= 1){ s += __shfl_down(s, off); s2 += __shfl_down(s2, off); }
  __shared__ float wsum[4][2];
  int wv = tid >> 6;
  if ((tid & 63) == 0){ wsum[wv][0] = s; wsum[wv][1] = s2; }
  __syncthreads();
  if (tid == 0){
    float S  = wsum[0][0]+wsum[1][0]+wsum[2][0]+wsum[3][0];
    float S2 = wsum[0][1]+wsum[1][1]+wsum[2][1]+wsum[3][1];
    atomicAdd(&dstats[2*d], S); atomicAdd(&dstats[2*d+1], S2);
  }
}

// ---------------- BN finalize: stats -> alpha,beta per channel ----------------
__global__ void k_bnfin(const float* __restrict__ stats, const float* __restrict__ g,
                        const float* __restrict__ b, int nchan, float count, float* __restrict__ ab){
  int c = threadIdx.x;
  if (c < nchan){
    float mean = stats[2*c] / count;
    float var  = stats[2*c+1] / count - mean*mean;
    float al = g[c] * rsqrtf(var + 1e-5f);
    float be = b[c] - mean * al;
    ab[2*c] = al; ab[2*c+1] = be;
  }
}

// ---------------- patch branch: t = zd+res, 8 rows/block, shuffle-reduced stats ----------------
__global__ __launch_bounds__(256) void k_patch(const float* __restrict__ xt, const float* __restrict__ Tn,
    const float* __restrict__ tb, float* __restrict__ t, float* __restrict__ pstats){
  __shared__ float xs[512];
  int blk = blockIdx.x, tid = threadIdx.x;
  int n0 = tid >> 4, qq = tid & 15;
  int n1 = n0 + 16;
  float tb0 = tb[n0*16 + qq], tb1 = tb[n1*16 + qq];
  float s0 = 0.f, q0 = 0.f, s1 = 0.f, q1 = 0.f;
  for (int rr = 0; rr < 8; rr++){
    int r = blk*8 + rr;
    __syncthreads();
    xs[tid]       = xt[(size_t)r*512 + tid];
    xs[tid + 256] = xt[(size_t)r*512 + tid + 256];
    __syncthreads();
    float a0 = tb0;
    #pragma unroll
    for (int q2 = 0; q2 < 16; q2++) a0 += xs[n0*16 + q2] * Tn[n0*256 + q2*16 + qq];
    t[(size_t)r*512 + tid] = a0; s0 += a0; q0 += a0*a0;
    float a1 = tb1;
    #pragma unroll
    for (int q2 = 0; q2 < 16; q2++) a1 += xs[n1*16 + q2] * Tn[n1*256 + q2*16 + qq];
    t[(size_t)r*512 + tid + 256] = a1; s1 += a1; q1 += a1*a1;
  }
  #pragma unroll
  for (int off = 1; off < 16; off <<= 1){
    s0 += __shfl_xor(s0, off); q0 += __shfl_xor(q0, off);
    s1 += __shfl_xor(s1, off); q1 += __shfl_xor(q1, off);
  }
  if (qq == 0){
    atomicAdd(&pstats[2*n0], s0); atomicAdd(&pstats[2*n0+1], q0);
    atomicAdd(&pstats[2*n1], s1); atomicAdd(&pstats[2*n1+1], q1);
  }
}

// ---------------- z2 = gelu(bn(t)) [in-place]; zc_pre = conv3(z2); 8 rows/block ----------------
__global__ __launch_bounds__(256) void k_z2(float* __restrict__ t, float* __restrict__ zcp,
    const float* __restrict__ abp, const float* __restrict__ wdc1,
    const float* __restrict__ bdc1, float* __restrict__ depstats){
  __shared__ float zs[512];
  int blk = blockIdx.x, tid = threadIdx.x;
  int n0 = tid >> 4, qq = tid & 15;
  int n1 = n0 + 16;
  float al0 = abp[2*n0], be0 = abp[2*n0+1], al1 = abp[2*n1], be1 = abp[2*n1+1];
  float w00 = wdc1[n0*3], w01 = wdc1[n0*3+1], w02 = wdc1[n0*3+2], bb0 = bdc1[n0];
  float w10 = wdc1[n1*3], w11 = wdc1[n1*3+1], w12 = wdc1[n1*3+2], bb1 = bdc1[n1];
  float s0 = 0.f, q0 = 0.f, s1 = 0.f, q1 = 0.f;
  for (int rr = 0; rr < 8; rr++){
    int r = blk*8 + rr;
    __syncthreads();
    float v0 = t[(size_t)r*512 + tid];
    float v1 = t[(size_t)r*512 + tid + 256];
    zs[tid]       = gelu_f(al0*v0 + be0);
    zs[tid + 256] = gelu_f(al1*v1 + be1);
    __syncthreads();
    float z0 = zs[tid];
    float l0 = qq > 0  ? zs[tid-1] : 0.f;
    float r0 = qq < 15 ? zs[tid+1] : 0.f;
    float cv0 = w00*l0 + w01*z0 + w02*r0 + bb0;
    zcp[(size_t)r*512 + tid] = cv0;
    t[(size_t)r*512 + tid] = z0;
    s0 += cv0; q0 += cv0*cv0;
    float z1v = zs[tid + 256];
    float l1 = qq > 0  ? zs[tid+255] : 0.f;
    float r1 = qq < 15 ? zs[tid+257] : 0.f;
    float cv1 = w10*l1 + w11*z1v + w12*r1 + bb1;
    zcp[(size_t)r*512 + tid + 256] = cv1;
    t[(size_t)r*512 + tid + 256] = z1v;
    s1 += cv1; q1 += cv1*cv1;
  }
  #pragma unroll
  for (int off = 1; off < 16; off <<= 1){
    s0 += __shfl_xor(s0, off); q0 += __shfl_xor(q0, off);
    s1 += __shfl_xor(s1, off); q1 += __shfl_xor(q1, off);
  }
  if (qq == 0){
    atomicAdd(&depstats[2*n0], s0); atomicAdd(&depstats[2*n0+1], q0);
    atomicAdd(&depstats[2*n1], s1); atomicAdd(&depstats[2*n1+1], q1);
  }
}

// ---------------- z2f = gelu(bn(zcp)) + z2  (in-place over zcp) ----------------
__global__ __launch_bounds__(256) void k_z2f(float* __restrict__ zcp, const float* __restrict__ z2,
    const float* __restrict__ ab){
  int idx = blockIdx.x*256 + threadIdx.x;
  int n = (idx >> 4) & 31;
  zcp[idx] = gelu_f(ab[2*n]*zcp[idx] + ab[2*n+1]) + z2[idx];
}

// ---------------- attention scalar per row ----------------
__global__ __launch_bounds__(256) void k_att(const float* __restrict__ z1, const float* __restrict__ z2f,
    const float* __restrict__ D2, const float* __restrict__ adww,
    const float* __restrict__ adwb, float* __restrict__ att, float* __restrict__ astats){
  int r = blockIdx.x, tid = threadIdx.x;
  float acc[5] = {};
  for (int it = 0; it < 2; ++it){
    int m = tid + it*256;
    float p = z1[(size_t)r*512 + m] * z2f[(size_t)r*512 + m];
    #pragma unroll
    for (int kf = 0; kf < 5; kf++) acc[kf] += p * D2[kf*512 + m];
  }
  for (int off = 32; off; off >>= 1){
    #pragma unroll
    for (int kf = 0; kf < 5; kf++) acc[kf] += __shfl_down(acc[kf], off);
  }
  __shared__ float wsum[4][5];
  if ((tid & 63) == 0){ for (int kf = 0; kf < 5; kf++) wsum[tid>>6][kf] = acc[kf]; }
  __syncthreads();
  if (tid == 0){
    const float rs = 22.627416997969522f;   // sqrt(512)
    float a = adwb[0];
    for (int kf = 0; kf < 5; kf++){
      float low = wsum[0][kf]+wsum[1][kf]+wsum[2][kf]+wsum[3][kf];
      float so = (kf == 0) ? 0.5f/rs : 0.70710678118654752440f/rs;
      a += low * so * adww[kf];
    }
    att[r] = a;
    atomicAdd(&astats[0], a); atomicAdd(&astats[1], a*a);
  }
}

// ---------------- att BN + gelu + softmax over d ----------------
__global__ __launch_bounds__(256) void k_attfin(const float* __restrict__ att, const float* __restrict__ astats,
    const float* __restrict__ ag, const float* __restrict__ abb,
    const float* __restrict__ acw, const float* __restrict__ acb,
    float* __restrict__ att1){
  int b = threadIdx.x;
  float mean = astats[0] / 5376.0f;
  float var  = astats[1] / 5376.0f - mean*mean;
  float al = ag[0] * rsqrtf(var + 1e-5f);
  float bb = abb[0];
  float cw = acw[0], cb2 = acb[0];
  float v[DV]; float mx = -1e30f;
  for (int d = 0; d < DV; d++){
    float a = att[b*DV + d];
    a = gelu_f(al*(a - mean) + bb);
    a = a*cw + cb2;
    v[d] = a; mx = fmaxf(mx, a);
  }
  float s = 0.f;
  for (int d = 0; d < DV; d++){ v[d] = expf(v[d] - mx); s += v[d]; }
  float inv = 1.0f / s;
  for (int d = 0; d < DV; d++) att1[b*DV + d] = v[d] * inv;
}

// ---------------- build BcatT (256x512): rows 0..95 Wm1^T, 128..223 M^T, rest 0 ----------------
__global__ __launch_bounds__(256) void k_bcat(const float* __restrict__ Wm1, const float* __restrict__ M,
                                              float* __restrict__ BcatT){
  int i = blockIdx.x*256 + threadIdx.x;   // 131072
  int c = i >> 9, m = i & 511;
  float v = 0.f;
  if (c < 96) v = Wm1[m*96 + c];
  else if (c >= 128 && c < 224) v = M[m*96 + (c - 128)];
  BcatT[i] = v;
}

// ---------------- out = Zres + c + gelu(H + bm1) @ Wm2 + bm2, 16 rows/block ----------------
__global__ __launch_bounds__(256) void k_out(const float* __restrict__ Hcat, const float* __restrict__ c,
    const float* __restrict__ S, void* __restrict__ outv, const int* __restrict__ flag){
  const float* bm1 = S + S_BM1;
  const float* Wm2 = S + S_WM2;
  const float* bm2 = S + S_BM2;
  __shared__ float W2s[96*96];
  __shared__ float Hs[16][100];
  int blk = blockIdx.x, tid = threadIdx.x;
  int r0 = blk*16;
  for (int i = tid; i < 96*96; i += 256) W2s[i] = Wm2[i];
  for (int i = tid; i < 16*96; i += 256){
    int rr = i / 96, col = i - rr*96;
    Hs[rr][col] = gelu_f(Hcat[(size_t)(r0+rr)*256 + col] + bm1[col]);
  }
  __syncthreads();
  int rr = tid >> 4, c0 = (tid & 15)*6;
  float acc[6] = {};
  for (int k = 0; k < 96; k++){
    float h = Hs[rr][k];
    #pragma unroll
    for (int j = 0; j < 6; j++) acc[j] += h * W2s[k*96 + c0 + j];
  }
  int r = r0 + rr;
  int b = r / DV, d = r - b*DV;
  int mode = *flag;
  #pragma unroll
  for (int j = 0; j < 6; j++){
    int p = c0 + j;
    float val = Hcat[(size_t)r*256 + 128 + p] + c[p] + acc[j] + bm2[p];
    size_t oi = ((size_t)b*96 + p)*DV + d;
    if (mode) ((float*)outv)[oi] = val;
    else ((__hip_bfloat16*)outv)[oi] = __float2bfloat16(val);
  }
}

extern "C" void kernel_launch(void* const* d_in, const int* in_sizes, int n_in,
                              void* d_out, int out_size, void* d_ws, size_t ws_size,
                              hipStream_t stream) {
  float* w = (float*)d_ws;
  float* xt   = w + OFF_XT;
  float* zA   = w + OFF_ZA;
  float* z1   = w + OFF_Z1;
  float* zcp  = w + OFF_ZCP;
  float* D2   = w + OFF_D2;
  float* D3   = w + OFF_D3;
  float* Mb   = w + OFF_M;
  float* Tn   = w + OFF_TN;
  float* tb   = w + OFF_TB;
  float* cb   = w + OFF_C;
  float* en   = w + OFF_EN;
  float* nrm  = w + OFF_NORM;
  float* att  = w + OFF_ATT;
  float* att1 = w + OFF_ATT1;
  float* stat = w + OFF_STAT;
  float* abd  = w + OFF_ABD;
  float* abp  = w + OFF_ABP;
  float* abdep= w + OFF_ABDEP;
  int*   flag = (int*)(w + OFF_FLAG);
  float* S    = w + OFF_STG;
  float* Hcat = zA;               // 5376x256, alias (zA dead after z2f)
  float* BcatT= zA + 1500000;     // 256x512, alias

  Ptrs ptrs;
  for (int i = 0; i < 30; i++) ptrs.p[i] = d_in[i];

  k_init<<<1, 256, 0, stream>>>((const unsigned*)d_in[13], stat, cb, flag);
  k_stage<<<3338, 256, 0, stream>>>(ptrs, S, flag);
  k_transpose<<<B_, 256, 0, stream>>>(d_in[0], xt, flag);
  k_dctmats<<<1024, 256, 0, stream>>>(D2, D3);
  k_foldmats<<<232, 256, 0, stream>>>(S, Mb, cb, Tn, tb);

  k_gemm<0><<<dim3(8,84), 256, 0, stream>>>(xt, nullptr, D2, zA, nullptr, nullptr, nullptr, nullptr, 512);
  k_energy<<<NROW/4, 256, 0, stream>>>(zA, en);
  k_med<<<1, 256, 0, stream>>>(en, nrm);
  k_rank<<<84, 256, 0, stream>>>(nrm, S+S_THR, stat);
  k_maskgelu<<<NROW, 256, 0, stream>>>(zA, nrm, stat, S+S_THR, S+S_WDCT, S+S_BDCT, stat + 0);
  k_bnfin<<<1, 64, 0, stream>>>(stat + 0, S+S_GD, S+S_BDN, DV, 131072.0f, abd);
  k_gemm<1><<<dim3(8,84), 256, 0, stream>>>(zA, nullptr, D3, z1, abd, xt, S+S_WDCT, S+S_BDCT, 512);

  k_patch<<<NROW/8, 256, 0, stream>>>(xt, Tn, tb, zA, stat + 42);
  k_bnfin<<<1, 64, 0, stream>>>(stat + 42, S+S_GP, S+S_BP, NP, 86016.0f, abp);
  k_z2<<<NROW/8, 256, 0, stream>>>(zA, zcp, abp, S+S_WDC1, S+S_BDC1, stat + 106);
  k_bnfin<<<1, 64, 0, stream>>>(stat + 106, S+S_GDEP, S+S_BDEP, NP, 86016.0f, abdep);
  k_z2f<<<NROW*2, 256, 0, stream>>>(zcp, zA, abdep);

  k_att<<<NROW, 256, 0, stream>>>(z1, zcp, D2, S+S_ADWW, S+S_ADWB, att, stat + 170);
  k_attfin<<<1, 256, 0, stream>>>(att, stat + 170, S+S_AG, S+S_AB2, S+S_ACW, S+S_ACB, att1);

  k_bcat<<<512, 256, 0, stream>>>(S+S_WM1, Mb, BcatT);
  k_gemm<3><<<dim3(4,84), 256, 0, stream>>>(z1, zcp, BcatT, Hcat, att1, xt, nullptr, nullptr, 256);
  k_out<<<NROW/16, 256, 0, stream>>>(Hcat, cb, S, d_out, flag);
}

// Round 4
// 694.558 us; speedup vs baseline: 1.8830x; 1.2337x over previous
//
#include <hip/hip_runtime.h>
#include <hip/hip_bf16.h>

#define B_    256
#define L_    512
#define DV    21
#define NROW  5376       // B_*DV
#define NP    32
#define PP    16
#define PRED_ 96

// ---------------- workspace layout (float indices) ----------------
static const size_t OFF_XT    = 0;          // 5376x512 f32
static const size_t OFF_ZA    = 2752512;    // z_dct -> z -> t -> z2 -> Hcat/BcatT (aliased over time)
static const size_t OFF_Z1    = 5505024;
static const size_t OFF_ZCP   = 8257536;    // zc_pre -> z2f (in-place)
static const size_t OFF_D2    = 11010048;   // 512x512
static const size_t OFF_D3    = 11272192;
static const size_t OFF_M     = 11534336;   // 512x96 folded linres
static const size_t OFF_TN    = 11583488;   // 32x16x16
static const size_t OFF_TB    = 11591680;   // 32x16
static const size_t OFF_C     = 11592192;   // 96 (pad 128)
static const size_t OFF_EN    = 11592320;   // 5376
static const size_t OFF_NORM  = 11597696;
static const size_t OFF_ATT   = 11603072;
static const size_t OFF_ATT1  = 11608448;   // also aliases dvec (512) before k_attfin writes att1
static const size_t OFF_STAT  = 11613824;   // 256: [0..41]dct [42..105]patch [106..169]dep [200],[201]=thr order stats
static const size_t OFF_ABD   = 11614080;   // 64
static const size_t OFF_ABP   = 11614144;   // 64
static const size_t OFF_ABDEP = 11614208;   // 64
static const size_t OFF_FLAG  = 11614272;   // int mode flag (1=f32 inputs, 0=bf16)
static const size_t OFF_STG   = 11614336;   // staged f32 weights (854480)
// total 12468816 floats = 49.9 MB
// aliases inside OFF_ZA region (live only after z2f):
//   Hcat  = OFF_ZA            (5376 x 256)
//   BcatT = OFF_ZA + 1500000  (256 x 512)

// staged-weight offsets (relative to OFF_STG)
static const int S_WDCT=0, S_BDCT=24, S_WE=48, S_BE=4144, S_WL=4400, S_BL=790832,
  S_WD=790928, S_BDRES=795024, S_WDC=795040, S_BDC=795552, S_WDC1=795584, S_BDC1=795680,
  S_GD=795712, S_BDN=795736, S_GP=795760, S_BP=795792, S_GDEP=795824, S_BDEP=795856,
  S_THR=795888, S_WM1=795892, S_BM1=845044, S_WM2=845140, S_BM2=854356,
  S_ADWW=854452, S_ADWB=854460, S_ACW=854464, S_ACB=854468, S_AG=854472, S_AB2=854476;

struct Ptrs { const void* p[30]; };

__device__ __forceinline__ float bf2f(unsigned short h){
  unsigned u = ((unsigned)h) << 16;
  return __uint_as_float(u);
}
__device__ __forceinline__ float gelu_f(float x){ return 0.5f*x*(1.0f+erff(x*0.70710678118654752440f)); }

// ---------------- init: zero stats + c accum + detect input dtype ----------------
__global__ void k_init(const unsigned* __restrict__ gones, float* __restrict__ stat,
                       float* __restrict__ c, int* __restrict__ flag){
  stat[threadIdx.x] = 0.0f;
  if (threadIdx.x < 128) c[threadIdx.x] = 0.0f;
  if (threadIdx.x == 0) *flag = (gones[0] == 0x3F800000u) ? 1 : 0;
}

// ---------------- stage all weights (inputs 1..29) to f32 ----------------
__global__ __launch_bounds__(256) void k_stage(Ptrs ptrs, float* __restrict__ dst, const int* __restrict__ flag){
  const int cnt[29] = {21,21,4096,256,786432,96,4096,16,512,32,96,32,21,21,32,32,32,32,1,49152,96,9216,96,5,1,1,1,1,1};
  const int off[29] = {S_WDCT,S_BDCT,S_WE,S_BE,S_WL,S_BL,S_WD,S_BDRES,S_WDC,S_BDC,S_WDC1,S_BDC1,
                       S_GD,S_BDN,S_GP,S_BP,S_GDEP,S_BDEP,S_THR,S_WM1,S_BM1,S_WM2,S_BM2,
                       S_ADWW,S_ADWB,S_ACW,S_ACB,S_AG,S_AB2};
  int mode = *flag;
  int gid = blockIdx.x*256 + threadIdx.x;
  int a = -1, loc = 0, base = 0;
  #pragma unroll
  for (int i = 0; i < 29; i++){
    if (a < 0 && gid < base + cnt[i]){ a = i; loc = gid - base; }
    base += cnt[i];
  }
  if (a < 0) return;
  const void* s = ptrs.p[a+1];
  float v = mode ? ((const float*)s)[loc] : bf2f(((const unsigned short*)s)[loc]);
  dst[off[a] + loc] = v;
}

// ---------------- transpose x (B,L,D) -> xt (B*D, L) f32, dual dtype ----------------
__global__ __launch_bounds__(256) void k_transpose(const void* __restrict__ x, float* __restrict__ xt,
                                                   const int* __restrict__ flag){
  __shared__ float xs[L_*DV];
  int mode = *flag;
  int b = blockIdx.x;
  if (mode){
    const float* xp = (const float*)x + (size_t)b*(L_*DV);
    for (int i = threadIdx.x; i < L_*DV; i += 256) xs[i] = xp[i];
  } else {
    const unsigned short* xp = (const unsigned short*)x + (size_t)b*(L_*DV);
    for (int i = threadIdx.x; i < L_*DV; i += 256) xs[i] = bf2f(xp[i]);
  }
  __syncthreads();
  float* op = xt + (size_t)b*(L_*DV);
  for (int i = threadIdx.x; i < L_*DV; i += 256){
    int l = i & 511, d = i >> 9;
    op[i] = xs[l*DV + d];
  }
}

// ---------------- DCT matrices (exact integer range reduction) ----------------
__global__ __launch_bounds__(256) void k_dctmats(float* __restrict__ D2, float* __restrict__ D3){
  int i = blockIdx.x*256 + threadIdx.x;
  int kk = i >> 9, m = i & 511;
  const float PIo = 3.14159265358979323846f / 1024.0f;
  int a = ((2*m+1)*kk) & 2047;
  D2[i] = 2.0f * cosf(PIo * (float)a);
  int l = kk, k = m;
  int a2 = ((2*l+1)*k) & 2047;
  float w0 = (k==0) ? 0.5f : 1.0f;
  D3[i] = cosf(PIo * (float)a2) * w0 * (1.0f/512.0f);
}

// ---------------- dvec[m] = sum_k 2cos(pi(2m+1)k/1024) * s_ortho[k] * a_dw_w[k] ----------------
// (a_dw_b cancels exactly through the BatchNorm over att -> skipped)
__global__ void k_dvec(const float* __restrict__ S, float* __restrict__ dvec){
  int m = blockIdx.x*256 + threadIdx.x;   // 0..511
  const float PIo = 3.14159265358979323846f / 1024.0f;
  const float rs = 22.627416997969522f;   // sqrt(512)
  float s = 0.f;
  #pragma unroll
  for (int k = 0; k < 5; k++){
    float sk = ((k == 0) ? 0.5f : 0.70710678118654752440f) / rs;
    int a = ((2*m+1)*k) & 2047;
    s += 2.0f * cosf(PIo * (float)a) * sk * S[S_ADWW + k];
  }
  dvec[m] = s;
}

// ---------------- fold patch-branch weights (all staged f32) ----------------
// blocks 0..191: M   blocks 192..199: c partials (atomic)   blocks 200..231: Tn/tb
__global__ __launch_bounds__(256) void k_foldmats(const float* __restrict__ S,
    float* __restrict__ M, float* __restrict__ c, float* __restrict__ Tn, float* __restrict__ tb){
  const float* We = S + S_WE;  const float* be = S + S_BE;
  const float* Wl = S + S_WL;  const float* bl = S + S_BL;
  const float* Wd = S + S_WD;  const float* bdres = S + S_BDRES;
  const float* wdc = S + S_WDC; const float* bdc = S + S_BDC;
  int blk = blockIdx.x, tid = threadIdx.x;
  if (blk < 192){
    int gid = blk*256 + tid;        // 49152 = 512*96
    int l = gid/96, p = gid - l*96;
    int n = l>>4, q = l&15;
    float acc = 0.f;
    for (int j=0;j<256;j++) acc += We[q*256+j] * Wl[(size_t)(n*256+j)*96 + p];
    M[(size_t)l*96+p] = acc;
  } else if (blk < 200){
    if (tid < 96){
      int J0 = (blk-192)*1024;
      float acc = (blk == 192) ? bl[tid] : 0.0f;
      for (int J = J0; J < J0+1024; J++) acc += be[J & 255] * Wl[(size_t)J*96 + tid];
      atomicAdd(&c[tid], acc);
    }
  } else {
    int n = blk - 200;              // 0..31
    int q2 = tid>>4, q = tid&15;    // q2 = patch pos, q = output
    float R = 0.f;
    for (int j=0;j<256;j++) R += We[q2*256+j] * Wd[j*16+q];
    float G = 0.f;
    for (int p=0;p<16;p++) G += We[q2*256 + q*16 + p] * wdc[n*16+p];
    Tn[n*256 + q2*16 + q] = R + G;
    if (tid < 16){
      float rb = bdres[tid];
      for (int j=0;j<256;j++) rb += be[j] * Wd[j*16+tid];
      float gb = bdc[n];
      for (int p=0;p<16;p++) gb += be[tid*16+p] * wdc[n*16+p];
      tb[n*16+tid] = rb + gb;
    }
  }
}

// ---------------- tiled f32 GEMM: C[r,col] = sum_m A'[r,m]*Bm[col*512+m] ----------------
// MODE 0: plain.  MODE 1: A' = alpha_d*A+beta_d, epilogue += xt*w_dct+b_dct.
// MODE 3: blockIdx.x<2 -> A' = att*A + (1-att)*A2 ; else A' = xt.  (MLP/zres fused GEMM)
template<int MODE>
__global__ __launch_bounds__(256) void k_gemm(
    const float* __restrict__ A, const float* __restrict__ A2,
    const float* __restrict__ Bm, float* __restrict__ C,
    const float* __restrict__ ab, const float* __restrict__ xt,
    const float* __restrict__ wdct, const float* __restrict__ bdct, int Cstride){
  __shared__ float As[16][68];   // pad 68 keeps 16B alignment for float4 reads
  __shared__ float Bs[16][68];
  int tid = threadIdx.x;
  int tx = tid & 15, ty = tid >> 4;
  int rowBase = blockIdx.y * 64;
  int colBase = blockIdx.x * 64;
  int lr = tid >> 2;
  int lk = (tid & 3) << 2;
  float alpha = 1.f, beta = 0.f;
  bool mixA = false;
  if (MODE == 1){ int d = (rowBase + lr) % DV; alpha = ab[2*d]; beta = ab[2*d+1]; }
  if (MODE == 3){ mixA = (blockIdx.x < 2); if (mixA) alpha = ab[rowBase + lr]; }
  float acc[4][4] = {};
  for (int k0 = 0; k0 < 512; k0 += 16){
    float4 av;
    if (MODE == 3 && !mixA) av = *(const float4*)(xt + (size_t)(rowBase+lr)*512 + k0 + lk);
    else                    av = *(const float4*)(A  + (size_t)(rowBase+lr)*512 + k0 + lk);
    if (MODE == 1){ av.x = alpha*av.x+beta; av.y = alpha*av.y+beta; av.z = alpha*av.z+beta; av.w = alpha*av.w+beta; }
    if (MODE == 3 && mixA){
      float4 a2 = *(const float4*)(A2 + (size_t)(rowBase+lr)*512 + k0 + lk);
      float om = 1.0f - alpha;
      av.x = alpha*av.x + om*a2.x; av.y = alpha*av.y + om*a2.y;
      av.z = alpha*av.z + om*a2.z; av.w = alpha*av.w + om*a2.w;
    }
    As[lk+0][lr] = av.x; As[lk+1][lr] = av.y; As[lk+2][lr] = av.z; As[lk+3][lr] = av.w;
    float4 bv = *(const float4*)(Bm + (size_t)(colBase+lr)*512 + k0 + lk);
    Bs[lk+0][lr] = bv.x; Bs[lk+1][lr] = bv.y; Bs[lk+2][lr] = bv.z; Bs[lk+3][lr] = bv.w;
    __syncthreads();
    #pragma unroll
    for (int kk = 0; kk < 16; kk++){
      float4 a4 = *(const float4*)&As[kk][ty*4];
      float4 b4 = *(const float4*)&Bs[kk][tx*4];
      acc[0][0] += a4.x*b4.x; acc[0][1] += a4.x*b4.y; acc[0][2] += a4.x*b4.z; acc[0][3] += a4.x*b4.w;
      acc[1][0] += a4.y*b4.x; acc[1][1] += a4.y*b4.y; acc[1][2] += a4.y*b4.z; acc[1][3] += a4.y*b4.w;
      acc[2][0] += a4.z*b4.x; acc[2][1] += a4.z*b4.y; acc[2][2] += a4.z*b4.z; acc[2][3] += a4.z*b4.w;
      acc[3][0] += a4.w*b4.x; acc[3][1] += a4.w*b4.y; acc[3][2] += a4.w*b4.z; acc[3][3] += a4.w*b4.w;
    }
    __syncthreads();
  }
  #pragma unroll
  for (int i = 0; i < 4; i++){
    int r = rowBase + ty*4 + i;
    #pragma unroll
    for (int j = 0; j < 4; j++){
      int cc = colBase + tx*4 + j;
      float v = acc[i][j];
      if (MODE == 1){
        int d = r % DV;
        v += xt[(size_t)r*512 + cc] * wdct[d] + bdct[d];
      }
      C[(size_t)r*Cstride + cc] = v;
    }
  }
}

// ---------------- energy per row ----------------
__global__ __launch_bounds__(256) void k_energy(const float* __restrict__ z, float* __restrict__ e){
  int tid = threadIdx.x;
  int r = blockIdx.x*4 + (tid>>6);
  int lane = tid & 63;
  const float* p = z + (size_t)r*512;
  float s = 0.f;
  #pragma unroll
  for (int w = 0; w < 8; w++){ float v = p[lane + w*64]; s += v*v; }
  for (int off = 32; off; off >>= 1) s += __shfl_down(s, off);
  if (lane == 0) e[r] = s;
}

// ---------------- median per batch row + norm_e ----------------
__global__ __launch_bounds__(256) void k_med(const float* __restrict__ e, float* __restrict__ norm){
  int b = threadIdx.x;
  float v[DV];
  for (int d = 0; d < DV; d++) v[d] = e[b*DV + d];
  float med = 0.f;
  for (int i = 0; i < DV; i++){
    int rk = 0;
    for (int j = 0; j < DV; j++) rk += (v[j] < v[i]) || (v[j] == v[i] && j < i);
    if (rk == 10) med = v[i];
  }
  float den = med + 1e-6f;
  for (int d = 0; d < DV; d++) norm[b*DV + d] = v[d] / den;
}

// ---------------- distributed rank-count quantile: 16 candidates/block, 16-way scan ----------------
__global__ __launch_bounds__(256) void k_rank(const float* __restrict__ norm,
    const float* __restrict__ thrv, float* __restrict__ stat){
  int tid = threadIdx.x;
  int cand = tid >> 4, part = tid & 15;
  int idx = blockIdx.x*16 + cand;
  float val = norm[idx];
  int cnt = 0;
  int j0 = part*336;
  for (int j = j0; j < j0 + 336; ++j){
    float v = norm[j];
    cnt += (v < val) || (v == val && j < idx);
  }
  __shared__ int sc[16][17];
  sc[cand][part] = cnt;
  __syncthreads();
  if (part == 0){
    int rank = 0;
    #pragma unroll
    for (int i = 0; i < 16; i++) rank += sc[cand][i];
    float q = thrv[0];
    float pos = q * 5375.0f;
    int i0 = (int)floorf(pos);
    int i1 = (i0 + 1 > 5375) ? 5375 : i0 + 1;
    if (rank == i0) stat[200] = val;
    if (rank == i1) stat[201] = val;
  }
}

// ---------------- mask + scale + gelu + BN stats (in-place over zA) ----------------
__global__ __launch_bounds__(256) void k_maskgelu(float* __restrict__ zA, const float* __restrict__ norm,
    const float* __restrict__ stat, const float* __restrict__ thrv,
    const float* __restrict__ wdct, const float* __restrict__ bdct,
    float* __restrict__ dstats){
  int r = blockIdx.x, tid = threadIdx.x;
  int d = r % DV;
  float q = thrv[0];
  float pos = q * 5375.0f; float f = pos - floorf(pos);
  float thr = stat[200] + (stat[201] - stat[200]) * f;
  float mask = norm[r] > thr ? 1.0f : 0.0f;
  float w = wdct[d], b = bdct[d];
  float s = 0.f, s2 = 0.f;
  for (int i = tid; i < 512; i += 256){
    float v = zA[(size_t)r*512 + i] * mask * w + b;
    float g = gelu_f(v);
    zA[(size_t)r*512 + i] = g;
    s += g; s2 += g*g;
  }
  for (int off = 32; off; off >>= 1){ s += __shfl_down(s, off); s2 += __shfl_down(s2, off); }
  __shared__ float wsum[4][2];
  int wv = tid >> 6;
  if ((tid & 63) == 0){ wsum[wv][0] = s; wsum[wv][1] = s2; }
  __syncthreads();
  if (tid == 0){
    float S  = wsum[0][0]+wsum[1][0]+wsum[2][0]+wsum[3][0];
    float S2 = wsum[0][1]+wsum[1][1]+wsum[2][1]+wsum[3][1];
    atomicAdd(&dstats[2*d], S); atomicAdd(&dstats[2*d+1], S2);
  }
}

// ---------------- BN finalize: stats -> alpha,beta per channel ----------------
__global__ void k_bnfin(const float* __restrict__ stats, const float* __restrict__ g,
                        const float* __restrict__ b, int nchan, float count, float* __restrict__ ab){
  int c = threadIdx.x;
  if (c < nchan){
    float mean = stats[2*c] / count;
    float var  = stats[2*c+1] / count - mean*mean;
    float al = g[c] * rsqrtf(var + 1e-5f);
    float be = b[c] - mean * al;
    ab[2*c] = al; ab[2*c+1] = be;
  }
}

// ---------------- patch branch: t = zd+res, 8 rows/block, shuffle-reduced stats ----------------
__global__ __launch_bounds__(256) void k_patch(const float* __restrict__ xt, const float* __restrict__ Tn,
    const float* __restrict__ tb, float* __restrict__ t, float* __restrict__ pstats){
  __shared__ float xs[512];
  int blk = blockIdx.x, tid = threadIdx.x;
  int n0 = tid >> 4, qq = tid & 15;
  int n1 = n0 + 16;
  float tb0 = tb[n0*16 + qq], tb1 = tb[n1*16 + qq];
  float s0 = 0.f, q0 = 0.f, s1 = 0.f, q1 = 0.f;
  for (int rr = 0; rr < 8; rr++){
    int r = blk*8 + rr;
    __syncthreads();
    xs[tid]       = xt[(size_t)r*512 + tid];
    xs[tid + 256] = xt[(size_t)r*512 + tid + 256];
    __syncthreads();
    float a0 = tb0;
    #pragma unroll
    for (int q2 = 0; q2 < 16; q2++) a0 += xs[n0*16 + q2] * Tn[n0*256 + q2*16 + qq];
    t[(size_t)r*512 + tid] = a0; s0 += a0; q0 += a0*a0;
    float a1 = tb1;
    #pragma unroll
    for (int q2 = 0; q2 < 16; q2++) a1 += xs[n1*16 + q2] * Tn[n1*256 + q2*16 + qq];
    t[(size_t)r*512 + tid + 256] = a1; s1 += a1; q1 += a1*a1;
  }
  #pragma unroll
  for (int off = 1; off < 16; off <<= 1){
    s0 += __shfl_xor(s0, off); q0 += __shfl_xor(q0, off);
    s1 += __shfl_xor(s1, off); q1 += __shfl_xor(q1, off);
  }
  if (qq == 0){
    atomicAdd(&pstats[2*n0], s0); atomicAdd(&pstats[2*n0+1], q0);
    atomicAdd(&pstats[2*n1], s1); atomicAdd(&pstats[2*n1+1], q1);
  }
}

// ---------------- z2 = gelu(bn(t)) [in-place]; zc_pre = conv3(z2); 8 rows/block ----------------
__global__ __launch_bounds__(256) void k_z2(float* __restrict__ t, float* __restrict__ zcp,
    const float* __restrict__ abp, const float* __restrict__ wdc1,
    const float* __restrict__ bdc1, float* __restrict__ depstats){
  __shared__ float zs[512];
  int blk = blockIdx.x, tid = threadIdx.x;
  int n0 = tid >> 4, qq = tid & 15;
  int n1 = n0 + 16;
  float al0 = abp[2*n0], be0 = abp[2*n0+1], al1 = abp[2*n1], be1 = abp[2*n1+1];
  float w00 = wdc1[n0*3], w01 = wdc1[n0*3+1], w02 = wdc1[n0*3+2], bb0 = bdc1[n0];
  float w10 = wdc1[n1*3], w11 = wdc1[n1*3+1], w12 = wdc1[n1*3+2], bb1 = bdc1[n1];
  float s0 = 0.f, q0 = 0.f, s1 = 0.f, q1 = 0.f;
  for (int rr = 0; rr < 8; rr++){
    int r = blk*8 + rr;
    __syncthreads();
    float v0 = t[(size_t)r*512 + tid];
    float v1 = t[(size_t)r*512 + tid + 256];
    zs[tid]       = gelu_f(al0*v0 + be0);
    zs[tid + 256] = gelu_f(al1*v1 + be1);
    __syncthreads();
    float z0 = zs[tid];
    float l0 = qq > 0  ? zs[tid-1] : 0.f;
    float r0 = qq < 15 ? zs[tid+1] : 0.f;
    float cv0 = w00*l0 + w01*z0 + w02*r0 + bb0;
    zcp[(size_t)r*512 + tid] = cv0;
    t[(size_t)r*512 + tid] = z0;
    s0 += cv0; q0 += cv0*cv0;
    float z1v = zs[tid + 256];
    float l1 = qq > 0  ? zs[tid+255] : 0.f;
    float r1 = qq < 15 ? zs[tid+257] : 0.f;
    float cv1 = w10*l1 + w11*z1v + w12*r1 + bb1;
    zcp[(size_t)r*512 + tid + 256] = cv1;
    t[(size_t)r*512 + tid + 256] = z1v;
    s1 += cv1; q1 += cv1*cv1;
  }
  #pragma unroll
  for (int off = 1; off < 16; off <<= 1){
    s0 += __shfl_xor(s0, off); q0 += __shfl_xor(q0, off);
    s1 += __shfl_xor(s1, off); q1 += __shfl_xor(q1, off);
  }
  if (qq == 0){
    atomicAdd(&depstats[2*n0], s0); atomicAdd(&depstats[2*n0+1], q0);
    atomicAdd(&depstats[2*n1], s1); atomicAdd(&depstats[2*n1+1], q1);
  }
}

// ---------------- z2f = gelu(bn(zcp)) + z2  (in-place over zcp) ----------------
__global__ __launch_bounds__(256) void k_z2f(float* __restrict__ zcp, const float* __restrict__ z2,
    const float* __restrict__ ab){
  int idx = blockIdx.x*256 + threadIdx.x;
  int n = (idx >> 4) & 31;
  zcp[idx] = gelu_f(ab[2*n]*zcp[idx] + ab[2*n+1]) + z2[idx];
}

// ---------------- attention scalar per row: att[r] = sum_m z1*z2f*dvec  (no atomics) ----------------
__global__ __launch_bounds__(256) void k_att(const float* __restrict__ z1, const float* __restrict__ z2f,
    const float* __restrict__ dvec, float* __restrict__ att){
  int tid = threadIdx.x;
  int r = blockIdx.x*4 + (tid >> 6);
  int lane = tid & 63;
  const float* p1 = z1  + (size_t)r*512;
  const float* p2 = z2f + (size_t)r*512;
  float s = 0.f;
  #pragma unroll
  for (int w = 0; w < 8; w++){
    int m = lane + w*64;
    s += p1[m] * p2[m] * dvec[m];
  }
  for (int off = 32; off; off >>= 1) s += __shfl_down(s, off);
  if (lane == 0) att[r] = s;
}

// ---------------- att reduce + BN + gelu + softmax over d (single block) ----------------
__global__ __launch_bounds__(256) void k_attfin(const float* __restrict__ att, const float* __restrict__ S,
                                                float* __restrict__ att1){
  __shared__ float ws[4][2];
  int tid = threadIdx.x;
  float s = 0.f, s2 = 0.f;
  for (int i = tid; i < NROW; i += 256){ float a = att[i]; s += a; s2 += a*a; }
  for (int off = 32; off; off >>= 1){ s += __shfl_down(s, off); s2 += __shfl_down(s2, off); }
  if ((tid & 63) == 0){ ws[tid>>6][0] = s; ws[tid>>6][1] = s2; }
  __syncthreads();
  float S1 = ws[0][0]+ws[1][0]+ws[2][0]+ws[3][0];
  float S2 = ws[0][1]+ws[1][1]+ws[2][1]+ws[3][1];
  float mean = S1 / 5376.0f;
  float var  = S2 / 5376.0f - mean*mean;
  float al = S[S_AG] * rsqrtf(var + 1e-5f);
  float bb = S[S_AB2];
  float cw = S[S_ACW], cb2 = S[S_ACB];
  int b = tid;
  float v[DV]; float mx = -1e30f;
  for (int d = 0; d < DV; d++){
    float a = att[b*DV + d];
    a = gelu_f(al*(a - mean) + bb);
    a = a*cw + cb2;
    v[d] = a; mx = fmaxf(mx, a);
  }
  float ss = 0.f;
  for (int d = 0; d < DV; d++){ v[d] = expf(v[d] - mx); ss += v[d]; }
  float inv = 1.0f / ss;
  for (int d = 0; d < DV; d++) att1[b*DV + d] = v[d] * inv;
}

// ---------------- build BcatT (256x512): rows 0..95 Wm1^T, 128..223 M^T, rest 0 ----------------
__global__ __launch_bounds__(256) void k_bcat(const float* __restrict__ Wm1, const float* __restrict__ M,
                                              float* __restrict__ BcatT){
  int i = blockIdx.x*256 + threadIdx.x;   // 131072
  int c = i >> 9, m = i & 511;
  float v = 0.f;
  if (c < 96) v = Wm1[m*96 + c];
  else if (c >= 128 && c < 224) v = M[m*96 + (c - 128)];
  BcatT[i] = v;
}

// ---------------- out = Zres + c + gelu(H + bm1) @ Wm2 + bm2, 16 rows/block ----------------
__global__ __launch_bounds__(256) void k_out(const float* __restrict__ Hcat, const float* __restrict__ c,
    const float* __restrict__ S, void* __restrict__ outv, const int* __restrict__ flag){
  const float* bm1 = S + S_BM1;
  const float* Wm2 = S + S_WM2;
  const float* bm2 = S + S_BM2;
  __shared__ float W2s[96*96];
  __shared__ float Hs[16][100];
  int blk = blockIdx.x, tid = threadIdx.x;
  int r0 = blk*16;
  for (int i = tid; i < 96*96; i += 256) W2s[i] = Wm2[i];
  for (int i = tid; i < 16*96; i += 256){
    int rr = i / 96, col = i - rr*96;
    Hs[rr][col] = gelu_f(Hcat[(size_t)(r0+rr)*256 + col] + bm1[col]);
  }
  __syncthreads();
  int rr = tid >> 4, c0 = (tid & 15)*6;
  float acc[6] = {};
  for (int k = 0; k < 96; k++){
    float h = Hs[rr][k];
    #pragma unroll
    for (int j = 0; j < 6; j++) acc[j] += h * W2s[k*96 + c0 + j];
  }
  int r = r0 + rr;
  int b = r / DV, d = r - b*DV;
  int mode = *flag;
  #pragma unroll
  for (int j = 0; j < 6; j++){
    int p = c0 + j;
    float val = Hcat[(size_t)r*256 + 128 + p] + c[p] + acc[j] + bm2[p];
    size_t oi = ((size_t)b*96 + p)*DV + d;
    if (mode) ((float*)outv)[oi] = val;
    else ((__hip_bfloat16*)outv)[oi] = __float2bfloat16(val);
  }
}

extern "C" void kernel_launch(void* const* d_in, const int* in_sizes, int n_in,
                              void* d_out, int out_size, void* d_ws, size_t ws_size,
                              hipStream_t stream) {
  float* w = (float*)d_ws;
  float* xt   = w + OFF_XT;
  float* zA   = w + OFF_ZA;
  float* z1   = w + OFF_Z1;
  float* zcp  = w + OFF_ZCP;
  float* D2   = w + OFF_D2;
  float* D3   = w + OFF_D3;
  float* Mb   = w + OFF_M;
  float* Tn   = w + OFF_TN;
  float* tb   = w + OFF_TB;
  float* cb   = w + OFF_C;
  float* en   = w + OFF_EN;
  float* nrm  = w + OFF_NORM;
  float* att  = w + OFF_ATT;
  float* att1 = w + OFF_ATT1;
  float* dvec = w + OFF_ATT1;     // alias: dvec dead before att1 is written
  float* stat = w + OFF_STAT;
  float* abd  = w + OFF_ABD;
  float* abp  = w + OFF_ABP;
  float* abdep= w + OFF_ABDEP;
  int*   flag = (int*)(w + OFF_FLAG);
  float* S    = w + OFF_STG;
  float* Hcat = zA;               // 5376x256, alias (zA dead after z2f)
  float* BcatT= zA + 1500000;     // 256x512, alias

  Ptrs ptrs;
  for (int i = 0; i < 30; i++) ptrs.p[i] = d_in[i];

  k_init<<<1, 256, 0, stream>>>((const unsigned*)d_in[13], stat, cb, flag);
  k_stage<<<3338, 256, 0, stream>>>(ptrs, S, flag);
  k_transpose<<<B_, 256, 0, stream>>>(d_in[0], xt, flag);
  k_dctmats<<<1024, 256, 0, stream>>>(D2, D3);
  k_dvec<<<2, 256, 0, stream>>>(S, dvec);
  k_foldmats<<<232, 256, 0, stream>>>(S, Mb, cb, Tn, tb);

  k_gemm<0><<<dim3(8,84), 256, 0, stream>>>(xt, nullptr, D2, zA, nullptr, nullptr, nullptr, nullptr, 512);
  k_energy<<<NROW/4, 256, 0, stream>>>(zA, en);
  k_med<<<1, 256, 0, stream>>>(en, nrm);
  k_rank<<<336, 256, 0, stream>>>(nrm, S+S_THR, stat);
  k_maskgelu<<<NROW, 256, 0, stream>>>(zA, nrm, stat, S+S_THR, S+S_WDCT, S+S_BDCT, stat + 0);
  k_bnfin<<<1, 64, 0, stream>>>(stat + 0, S+S_GD, S+S_BDN, DV, 131072.0f, abd);
  k_gemm<1><<<dim3(8,84), 256, 0, stream>>>(zA, nullptr, D3, z1, abd, xt, S+S_WDCT, S+S_BDCT, 512);

  k_patch<<<NROW/8, 256, 0, stream>>>(xt, Tn, tb, zA, stat + 42);
  k_bnfin<<<1, 64, 0, stream>>>(stat + 42, S+S_GP, S+S_BP, NP, 86016.0f, abp);
  k_z2<<<NROW/8, 256, 0, stream>>>(zA, zcp, abp, S+S_WDC1, S+S_BDC1, stat + 106);
  k_bnfin<<<1, 64, 0, stream>>>(stat + 106, S+S_GDEP, S+S_BDEP, NP, 86016.0f, abdep);
  k_z2f<<<NROW*2, 256, 0, stream>>>(zcp, zA, abdep);

  k_att<<<NROW/4, 256, 0, stream>>>(z1, zcp, dvec, att);
  k_attfin<<<1, 256, 0, stream>>>(att, S, att1);

  k_bcat<<<512, 256, 0, stream>>>(S+S_WM1, Mb, BcatT);
  k_gemm<3><<<dim3(4,84), 256, 0, stream>>>(z1, zcp, BcatT, Hcat, att1, xt, nullptr, nullptr, 256);
  k_out<<<NROW/16, 256, 0, stream>>>(Hcat, cb, S, d_out, flag);
}

// Round 5
// 577.577 us; speedup vs baseline: 2.2644x; 1.2025x over previous
//
#include <hip/hip_runtime.h>
#include <hip/hip_bf16.h>

#define B_    256
#define L_    512
#define DV    21
#define NROW  5376       // B_*DV
#define NP    32
#define PP    16
#define PRED_ 96

// ---------------- workspace layout (float indices) ----------------
static const size_t OFF_XT    = 0;          // 5376x512 f32
static const size_t OFF_ZA    = 2752512;    // z_dct -> z -> t -> z2 -> Hcat/BcatT (aliased over time)
static const size_t OFF_Z1    = 5505024;
static const size_t OFF_ZCP   = 8257536;    // zc_pre -> z2f (in-place)
static const size_t OFF_D2    = 11010048;   // 512x512
static const size_t OFF_D3    = 11272192;
static const size_t OFF_M     = 11534336;   // 512x96 folded linres
static const size_t OFF_TN    = 11583488;   // 32x16x16
static const size_t OFF_TB    = 11591680;   // 32x16
static const size_t OFF_C     = 11592192;   // 96 (pad 128)
static const size_t OFF_EN    = 11592320;   // 5376
static const size_t OFF_NORM  = 11597696;
static const size_t OFF_ATT   = 11603072;
static const size_t OFF_ATT1  = 11608448;   // also aliases dvec (512) before k_attfin writes att1
static const size_t OFF_STAT  = 11613824;   // 256: [0..41]dct [42..105]patch [106..169]dep [200],[201]=thr order stats
static const size_t OFF_ABD   = 11614080;   // 64
static const size_t OFF_ABP   = 11614144;   // 64
static const size_t OFF_ABDEP = 11614208;   // 64
static const size_t OFF_FLAG  = 11614272;   // int mode flag (1=f32 inputs, 0=bf16)
static const size_t OFF_STG   = 11614336;   // staged f32 weights (854480)
// total 12468816 floats = 49.9 MB
// aliases inside OFF_ZA region (live only after z2f):
//   Hcat  = OFF_ZA            (5376 x 256)
//   BcatT = OFF_ZA + 1500000  (256 x 512)

// staged-weight offsets (relative to OFF_STG)
static const int S_WDCT=0, S_BDCT=24, S_WE=48, S_BE=4144, S_WL=4400, S_BL=790832,
  S_WD=790928, S_BDRES=795024, S_WDC=795040, S_BDC=795552, S_WDC1=795584, S_BDC1=795680,
  S_GD=795712, S_BDN=795736, S_GP=795760, S_BP=795792, S_GDEP=795824, S_BDEP=795856,
  S_THR=795888, S_WM1=795892, S_BM1=845044, S_WM2=845140, S_BM2=854356,
  S_ADWW=854452, S_ADWB=854460, S_ACW=854464, S_ACB=854468, S_AG=854472, S_AB2=854476;

struct Ptrs { const void* p[30]; };

__device__ __forceinline__ float bf2f(unsigned short h){
  unsigned u = ((unsigned)h) << 16;
  return __uint_as_float(u);
}
__device__ __forceinline__ float gelu_f(float x){ return 0.5f*x*(1.0f+erff(x*0.70710678118654752440f)); }

// ---------------- init: zero stats/c/M + detect input dtype ----------------
// block 0: stat + c + flag.  blocks 1..192: zero M (49152 floats).
__global__ void k_init(const unsigned* __restrict__ gones, float* __restrict__ stat,
                       float* __restrict__ c, float* __restrict__ M, int* __restrict__ flag){
  if (blockIdx.x == 0){
    stat[threadIdx.x] = 0.0f;
    if (threadIdx.x < 128) c[threadIdx.x] = 0.0f;
    if (threadIdx.x == 0) *flag = (gones[0] == 0x3F800000u) ? 1 : 0;
  } else {
    M[(blockIdx.x-1)*256 + threadIdx.x] = 0.0f;
  }
}

// ---------------- stage all weights (inputs 1..29) to f32 ----------------
__global__ __launch_bounds__(256) void k_stage(Ptrs ptrs, float* __restrict__ dst, const int* __restrict__ flag){
  const int cnt[29] = {21,21,4096,256,786432,96,4096,16,512,32,96,32,21,21,32,32,32,32,1,49152,96,9216,96,5,1,1,1,1,1};
  const int off[29] = {S_WDCT,S_BDCT,S_WE,S_BE,S_WL,S_BL,S_WD,S_BDRES,S_WDC,S_BDC,S_WDC1,S_BDC1,
                       S_GD,S_BDN,S_GP,S_BP,S_GDEP,S_BDEP,S_THR,S_WM1,S_BM1,S_WM2,S_BM2,
                       S_ADWW,S_ADWB,S_ACW,S_ACB,S_AG,S_AB2};
  int mode = *flag;
  int gid = blockIdx.x*256 + threadIdx.x;
  int a = -1, loc = 0, base = 0;
  #pragma unroll
  for (int i = 0; i < 29; i++){
    if (a < 0 && gid < base + cnt[i]){ a = i; loc = gid - base; }
    base += cnt[i];
  }
  if (a < 0) return;
  const void* s = ptrs.p[a+1];
  float v = mode ? ((const float*)s)[loc] : bf2f(((const unsigned short*)s)[loc]);
  dst[off[a] + loc] = v;
}

// ---------------- transpose x (B,L,D) -> xt (B*D, L) f32, dual dtype ----------------
__global__ __launch_bounds__(256) void k_transpose(const void* __restrict__ x, float* __restrict__ xt,
                                                   const int* __restrict__ flag){
  __shared__ float xs[L_*DV];
  int mode = *flag;
  int b = blockIdx.x;
  if (mode){
    const float* xp = (const float*)x + (size_t)b*(L_*DV);
    for (int i = threadIdx.x; i < L_*DV; i += 256) xs[i] = xp[i];
  } else {
    const unsigned short* xp = (const unsigned short*)x + (size_t)b*(L_*DV);
    for (int i = threadIdx.x; i < L_*DV; i += 256) xs[i] = bf2f(xp[i]);
  }
  __syncthreads();
  float* op = xt + (size_t)b*(L_*DV);
  for (int i = threadIdx.x; i < L_*DV; i += 256){
    int l = i & 511, d = i >> 9;
    op[i] = xs[l*DV + d];
  }
}

// ---------------- DCT matrices (exact integer range reduction) ----------------
__global__ __launch_bounds__(256) void k_dctmats(float* __restrict__ D2, float* __restrict__ D3){
  int i = blockIdx.x*256 + threadIdx.x;
  int kk = i >> 9, m = i & 511;
  const float PIo = 3.14159265358979323846f / 1024.0f;
  int a = ((2*m+1)*kk) & 2047;
  D2[i] = 2.0f * cosf(PIo * (float)a);
  int l = kk, k = m;
  int a2 = ((2*l+1)*k) & 2047;
  float w0 = (k==0) ? 0.5f : 1.0f;
  D3[i] = cosf(PIo * (float)a2) * w0 * (1.0f/512.0f);
}

// ---------------- dvec[m] = sum_k 2cos(pi(2m+1)k/1024) * s_ortho[k] * a_dw_w[k] ----------------
// (a_dw_b cancels exactly through the BatchNorm over att -> skipped)
__global__ void k_dvec(const float* __restrict__ S, float* __restrict__ dvec){
  int m = blockIdx.x*256 + threadIdx.x;   // 0..511
  const float PIo = 3.14159265358979323846f / 1024.0f;
  const float rs = 22.627416997969522f;   // sqrt(512)
  float s = 0.f;
  #pragma unroll
  for (int k = 0; k < 5; k++){
    float sk = ((k == 0) ? 0.5f : 0.70710678118654752440f) / rs;
    int a = ((2*m+1)*k) & 2047;
    s += 2.0f * cosf(PIo * (float)a) * sk * S[S_ADWW + k];
  }
  dvec[m] = s;
}

// ---------------- fold M = We@Wl blocks: K-split, 1536 blocks, atomic partials ----------------
__global__ __launch_bounds__(256) void k_foldM(const float* __restrict__ S, float* __restrict__ M){
  const float* We = S + S_WE;  const float* Wl = S + S_WL;
  int gid = blockIdx.x*256 + threadIdx.x;   // 0..49151 = (l,p)
  int l = gid/96, p = gid - l*96;
  int n = l>>4, q = l&15;
  int j0 = blockIdx.y*32;
  float acc = 0.f;
  #pragma unroll 8
  for (int j = j0; j < j0+32; j++) acc += We[q*256+j] * Wl[(size_t)(n*256+j)*96 + p];
  atomicAdd(&M[gid], acc);
}

// ---------------- fold c[p] = bl[p] + sum_J be[J&255]*Wl[J*96+p], 128 blocks ----------------
__global__ __launch_bounds__(256) void k_foldC(const float* __restrict__ S, float* __restrict__ c){
  const float* be = S + S_BE;  const float* Wl = S + S_WL;  const float* bl = S + S_BL;
  int t = threadIdx.x;
  int rp = t >> 7, p = t & 127;      // 2 J-rows in flight per iteration
  if (p >= 96) return;
  float acc = 0.f;
  int J0 = blockIdx.x*64;
  for (int j = 0; j < 64; j += 2){
    int J = J0 + j + rp;
    acc += be[J & 255] * Wl[(size_t)J*96 + p];
  }
  if (blockIdx.x == 0 && rp == 0) acc += bl[p];
  atomicAdd(&c[p], acc);
}

// ---------------- fold Tn/tb per n: all operands staged to LDS first ----------------
__global__ __launch_bounds__(256) void k_foldTn(const float* __restrict__ S,
    float* __restrict__ Tn, float* __restrict__ tb){
  __shared__ float WeS[4096];
  __shared__ float WdS[4096];
  __shared__ float wdcS[16];
  __shared__ float beS[256];
  __shared__ float bdresS[16];
  int n = blockIdx.x, tid = threadIdx.x;
  for (int i = tid; i < 4096; i += 256){ WeS[i] = S[S_WE+i]; WdS[i] = S[S_WD+i]; }
  beS[tid & 255] = S[S_BE + (tid & 255)];
  if (tid < 16){ wdcS[tid] = S[S_WDC + n*16 + tid]; bdresS[tid] = S[S_BDRES + tid]; }
  __syncthreads();
  int q2 = tid>>4, q = tid&15;
  float R = 0.f;
  for (int j = 0; j < 256; j++) R += WeS[q2*256+j] * WdS[j*16+q];
  float G = 0.f;
  #pragma unroll
  for (int p = 0; p < 16; p++) G += WeS[q2*256 + q*16 + p] * wdcS[p];
  Tn[n*256 + q2*16 + q] = R + G;
  if (tid < 16){
    float rb = bdresS[tid];
    for (int j = 0; j < 256; j++) rb += beS[j] * WdS[j*16+tid];
    float gb = S[S_BDC + n];
    #pragma unroll
    for (int p = 0; p < 16; p++) gb += beS[tid*16+p] * wdcS[p];
    tb[n*16+tid] = rb + gb;
  }
}

// ---------------- tiled f32 GEMM: C[r,col] = sum_m A'[r,m]*Bm[col*512+m] ----------------
// MODE 0: plain.  MODE 1: A' = alpha_d*A+beta_d, epilogue += xt*w_dct+b_dct.
// MODE 3: blockIdx.x<2 -> A' = att*A + (1-att)*A2 ; else A' = xt.  (MLP/zres fused GEMM)
template<int MODE>
__global__ __launch_bounds__(256) void k_gemm(
    const float* __restrict__ A, const float* __restrict__ A2,
    const float* __restrict__ Bm, float* __restrict__ C,
    const float* __restrict__ ab, const float* __restrict__ xt,
    const float* __restrict__ wdct, const float* __restrict__ bdct, int Cstride){
  __shared__ float As[16][68];   // pad 68 keeps 16B alignment for float4 reads
  __shared__ float Bs[16][68];
  int tid = threadIdx.x;
  int tx = tid & 15, ty = tid >> 4;
  int rowBase = blockIdx.y * 64;
  int colBase = blockIdx.x * 64;
  int lr = tid >> 2;
  int lk = (tid & 3) << 2;
  float alpha = 1.f, beta = 0.f;
  bool mixA = false;
  if (MODE == 1){ int d = (rowBase + lr) % DV; alpha = ab[2*d]; beta = ab[2*d+1]; }
  if (MODE == 3){ mixA = (blockIdx.x < 2); if (mixA) alpha = ab[rowBase + lr]; }
  float acc[4][4] = {};
  for (int k0 = 0; k0 < 512; k0 += 16){
    float4 av;
    if (MODE == 3 && !mixA) av = *(const float4*)(xt + (size_t)(rowBase+lr)*512 + k0 + lk);
    else                    av = *(const float4*)(A  + (size_t)(rowBase+lr)*512 + k0 + lk);
    if (MODE == 1){ av.x = alpha*av.x+beta; av.y = alpha*av.y+beta; av.z = alpha*av.z+beta; av.w = alpha*av.w+beta; }
    if (MODE == 3 && mixA){
      float4 a2 = *(const float4*)(A2 + (size_t)(rowBase+lr)*512 + k0 + lk);
      float om = 1.0f - alpha;
      av.x = alpha*av.x + om*a2.x; av.y = alpha*av.y + om*a2.y;
      av.z = alpha*av.z + om*a2.z; av.w = alpha*av.w + om*a2.w;
    }
    As[lk+0][lr] = av.x; As[lk+1][lr] = av.y; As[lk+2][lr] = av.z; As[lk+3][lr] = av.w;
    float4 bv = *(const float4*)(Bm + (size_t)(colBase+lr)*512 + k0 + lk);
    Bs[lk+0][lr] = bv.x; Bs[lk+1][lr] = bv.y; Bs[lk+2][lr] = bv.z; Bs[lk+3][lr] = bv.w;
    __syncthreads();
    #pragma unroll
    for (int kk = 0; kk < 16; kk++){
      float4 a4 = *(const float4*)&As[kk][ty*4];
      float4 b4 = *(const float4*)&Bs[kk][tx*4];
      acc[0][0] += a4.x*b4.x; acc[0][1] += a4.x*b4.y; acc[0][2] += a4.x*b4.z; acc[0][3] += a4.x*b4.w;
      acc[1][0] += a4.y*b4.x; acc[1][1] += a4.y*b4.y; acc[1][2] += a4.y*b4.z; acc[1][3] += a4.y*b4.w;
      acc[2][0] += a4.z*b4.x; acc[2][1] += a4.z*b4.y; acc[2][2] += a4.z*b4.z; acc[2][3] += a4.z*b4.w;
      acc[3][0] += a4.w*b4.x; acc[3][1] += a4.w*b4.y; acc[3][2] += a4.w*b4.z; acc[3][3] += a4.w*b4.w;
    }
    __syncthreads();
  }
  #pragma unroll
  for (int i = 0; i < 4; i++){
    int r = rowBase + ty*4 + i;
    #pragma unroll
    for (int j = 0; j < 4; j++){
      int cc = colBase + tx*4 + j;
      float v = acc[i][j];
      if (MODE == 1){
        int d = r % DV;
        v += xt[(size_t)r*512 + cc] * wdct[d] + bdct[d];
      }
      C[(size_t)r*Cstride + cc] = v;
    }
  }
}

// ---------------- energy per row ----------------
__global__ __launch_bounds__(256) void k_energy(const float* __restrict__ z, float* __restrict__ e){
  int tid = threadIdx.x;
  int r = blockIdx.x*4 + (tid>>6);
  int lane = tid & 63;
  const float* p = z + (size_t)r*512;
  float s = 0.f;
  #pragma unroll
  for (int w = 0; w < 8; w++){ float v = p[lane + w*64]; s += v*v; }
  for (int off = 32; off; off >>= 1) s += __shfl_down(s, off);
  if (lane == 0) e[r] = s;
}

// ---------------- median per batch row + norm_e ----------------
__global__ __launch_bounds__(256) void k_med(const float* __restrict__ e, float* __restrict__ norm){
  int b = threadIdx.x;
  float v[DV];
  for (int d = 0; d < DV; d++) v[d] = e[b*DV + d];
  float med = 0.f;
  for (int i = 0; i < DV; i++){
    int rk = 0;
    for (int j = 0; j < DV; j++) rk += (v[j] < v[i]) || (v[j] == v[i] && j < i);
    if (rk == 10) med = v[i];
  }
  float den = med + 1e-6f;
  for (int d = 0; d < DV; d++) norm[b*DV + d] = v[d] / den;
}

// ---------------- distributed rank-count quantile: 16 candidates/block, 16-way scan ----------------
__global__ __launch_bounds__(256) void k_rank(const float* __restrict__ norm,
    const float* __restrict__ thrv, float* __restrict__ stat){
  int tid = threadIdx.x;
  int cand = tid >> 4, part = tid & 15;
  int idx = blockIdx.x*16 + cand;
  float val = norm[idx];
  int cnt = 0;
  int j0 = part*336;
  for (int j = j0; j < j0 + 336; ++j){
    float v = norm[j];
    cnt += (v < val) || (v == val && j < idx);
  }
  __shared__ int sc[16][17];
  sc[cand][part] = cnt;
  __syncthreads();
  if (part == 0){
    int rank = 0;
    #pragma unroll
    for (int i = 0; i < 16; i++) rank += sc[cand][i];
    float q = thrv[0];
    float pos = q * 5375.0f;
    int i0 = (int)floorf(pos);
    int i1 = (i0 + 1 > 5375) ? 5375 : i0 + 1;
    if (rank == i0) stat[200] = val;
    if (rank == i1) stat[201] = val;
  }
}

// ---------------- mask + scale + gelu + BN stats (in-place over zA) ----------------
__global__ __launch_bounds__(256) void k_maskgelu(float* __restrict__ zA, const float* __restrict__ norm,
    const float* __restrict__ stat, const float* __restrict__ thrv,
    const float* __restrict__ wdct, const float* __restrict__ bdct,
    float* __restrict__ dstats){
  int r = blockIdx.x, tid = threadIdx.x;
  int d = r % DV;
  float q = thrv[0];
  float pos = q * 5375.0f; float f = pos - floorf(pos);
  float thr = stat[200] + (stat[201] - stat[200]) * f;
  float mask = norm[r] > thr ? 1.0f : 0.0f;
  float w = wdct[d], b = bdct[d];
  float s = 0.f, s2 = 0.f;
  for (int i = tid; i < 512; i += 256){
    float v = zA[(size_t)r*512 + i] * mask * w + b;
    float g = gelu_f(v);
    zA[(size_t)r*512 + i] = g;
    s += g; s2 += g*g;
  }
  for (int off = 32; off; off >>= 1){ s += __shfl_down(s, off); s2 += __shfl_down(s2, off); }
  __shared__ float wsum[4][2];
  int wv = tid >> 6;
  if ((tid & 63) == 0){ wsum[wv][0] = s; wsum[wv][1] = s2; }
  __syncthreads();
  if (tid == 0){
    float S  = wsum[0][0]+wsum[1][0]+wsum[2][0]+wsum[3][0];
    float S2 = wsum[0][1]+wsum[1][1]+wsum[2][1]+wsum[3][1];
    atomicAdd(&dstats[2*d], S); atomicAdd(&dstats[2*d+1], S2);
  }
}

// ---------------- BN finalize: stats -> alpha,beta per channel ----------------
__global__ void k_bnfin(const float* __restrict__ stats, const float* __restrict__ g,
                        const float* __restrict__ b, int nchan, float count, float* __restrict__ ab){
  int c = threadIdx.x;
  if (c < nchan){
    float mean = stats[2*c] / count;
    float var  = stats[2*c+1] / count - mean*mean;
    float al = g[c] * rsqrtf(var + 1e-5f);
    float be = b[c] - mean * al;
    ab[2*c] = al; ab[2*c+1] = be;
  }
}

// ---------------- patch branch: t = zd+res, 8 rows/block, shuffle-reduced stats ----------------
__global__ __launch_bounds__(256) void k_patch(const float* __restrict__ xt, const float* __restrict__ Tn,
    const float* __restrict__ tb, float* __restrict__ t, float* __restrict__ pstats){
  __shared__ float xs[512];
  int blk = blockIdx.x, tid = threadIdx.x;
  int n0 = tid >> 4, qq = tid & 15;
  int n1 = n0 + 16;
  float tb0 = tb[n0*16 + qq], tb1 = tb[n1*16 + qq];
  float s0 = 0.f, q0 = 0.f, s1 = 0.f, q1 = 0.f;
  for (int rr = 0; rr < 8; rr++){
    int r = blk*8 + rr;
    __syncthreads();
    xs[tid]       = xt[(size_t)r*512 + tid];
    xs[tid + 256] = xt[(size_t)r*512 + tid + 256];
    __syncthreads();
    float a0 = tb0;
    #pragma unroll
    for (int q2 = 0; q2 < 16; q2++) a0 += xs[n0*16 + q2] * Tn[n0*256 + q2*16 + qq];
    t[(size_t)r*512 + tid] = a0; s0 += a0; q0 += a0*a0;
    float a1 = tb1;
    #pragma unroll
    for (int q2 = 0; q2 < 16; q2++) a1 += xs[n1*16 + q2] * Tn[n1*256 + q2*16 + qq];
    t[(size_t)r*512 + tid + 256] = a1; s1 += a1; q1 += a1*a1;
  }
  #pragma unroll
  for (int off = 1; off < 16; off <<= 1){
    s0 += __shfl_xor(s0, off); q0 += __shfl_xor(q0, off);
    s1 += __shfl_xor(s1, off); q1 += __shfl_xor(q1, off);
  }
  if (qq == 0){
    atomicAdd(&pstats[2*n0], s0); atomicAdd(&pstats[2*n0+1], q0);
    atomicAdd(&pstats[2*n1], s1); atomicAdd(&pstats[2*n1+1], q1);
  }
}

// ---------------- z2 = gelu(bn(t)) [in-place]; zc_pre = conv3(z2); 8 rows/block ----------------
__global__ __launch_bounds__(256) void k_z2(float* __restrict__ t, float* __restrict__ zcp,
    const float* __restrict__ abp, const float* __restrict__ wdc1,
    const float* __restrict__ bdc1, float* __restrict__ depstats){
  __shared__ float zs[512];
  int blk = blockIdx.x, tid = threadIdx.x;
  int n0 = tid >> 4, qq = tid & 15;
  int n1 = n0 + 16;
  float al0 = abp[2*n0], be0 = abp[2*n0+1], al1 = abp[2*n1], be1 = abp[2*n1+1];
  float w00 = wdc1[n0*3], w01 = wdc1[n0*3+1], w02 = wdc1[n0*3+2], bb0 = bdc1[n0];
  float w10 = wdc1[n1*3], w11 = wdc1[n1*3+1], w12 = wdc1[n1*3+2], bb1 = bdc1[n1];
  float s0 = 0.f, q0 = 0.f, s1 = 0.f, q1 = 0.f;
  for (int rr = 0; rr < 8; rr++){
    int r = blk*8 + rr;
    __syncthreads();
    float v0 = t[(size_t)r*512 + tid];
    float v1 = t[(size_t)r*512 + tid + 256];
    zs[tid]       = gelu_f(al0*v0 + be0);
    zs[tid + 256] = gelu_f(al1*v1 + be1);
    __syncthreads();
    float z0 = zs[tid];
    float l0 = qq > 0  ? zs[tid-1] : 0.f;
    float r0 = qq < 15 ? zs[tid+1] : 0.f;
    float cv0 = w00*l0 + w01*z0 + w02*r0 + bb0;
    zcp[(size_t)r*512 + tid] = cv0;
    t[(size_t)r*512 + tid] = z0;
    s0 += cv0; q0 += cv0*cv0;
    float z1v = zs[tid + 256];
    float l1 = qq > 0  ? zs[tid+255] : 0.f;
    float r1 = qq < 15 ? zs[tid+257] : 0.f;
    float cv1 = w10*l1 + w11*z1v + w12*r1 + bb1;
    zcp[(size_t)r*512 + tid + 256] = cv1;
    t[(size_t)r*512 + tid + 256] = z1v;
    s1 += cv1; q1 += cv1*cv1;
  }
  #pragma unroll
  for (int off = 1; off < 16; off <<= 1){
    s0 += __shfl_xor(s0, off); q0 += __shfl_xor(q0, off);
    s1 += __shfl_xor(s1, off); q1 += __shfl_xor(q1, off);
  }
  if (qq == 0){
    atomicAdd(&depstats[2*n0], s0); atomicAdd(&depstats[2*n0+1], q0);
    atomicAdd(&depstats[2*n1], s1); atomicAdd(&depstats[2*n1+1], q1);
  }
}

// ---------------- z2f = gelu(bn(zcp)) + z2  (in-place over zcp) ----------------
__global__ __launch_bounds__(256) void k_z2f(float* __restrict__ zcp, const float* __restrict__ z2,
    const float* __restrict__ ab){
  int idx = blockIdx.x*256 + threadIdx.x;
  int n = (idx >> 4) & 31;
  zcp[idx] = gelu_f(ab[2*n]*zcp[idx] + ab[2*n+1]) + z2[idx];
}

// ---------------- attention scalar per row: att[r] = sum_m z1*z2f*dvec  (no atomics) ----------------
__global__ __launch_bounds__(256) void k_att(const float* __restrict__ z1, const float* __restrict__ z2f,
    const float* __restrict__ dvec, float* __restrict__ att){
  int tid = threadIdx.x;
  int r = blockIdx.x*4 + (tid >> 6);
  int lane = tid & 63;
  const float* p1 = z1  + (size_t)r*512;
  const float* p2 = z2f + (size_t)r*512;
  float s = 0.f;
  #pragma unroll
  for (int w = 0; w < 8; w++){
    int m = lane + w*64;
    s += p1[m] * p2[m] * dvec[m];
  }
  for (int off = 32; off; off >>= 1) s += __shfl_down(s, off);
  if (lane == 0) att[r] = s;
}

// ---------------- att reduce + BN + gelu + softmax over d (single block) ----------------
__global__ __launch_bounds__(256) void k_attfin(const float* __restrict__ att, const float* __restrict__ S,
                                                float* __restrict__ att1){
  __shared__ float ws[4][2];
  int tid = threadIdx.x;
  float s = 0.f, s2 = 0.f;
  for (int i = tid; i < NROW; i += 256){ float a = att[i]; s += a; s2 += a*a; }
  for (int off = 32; off; off >>= 1){ s += __shfl_down(s, off); s2 += __shfl_down(s2, off); }
  if ((tid & 63) == 0){ ws[tid>>6][0] = s; ws[tid>>6][1] = s2; }
  __syncthreads();
  float S1 = ws[0][0]+ws[1][0]+ws[2][0]+ws[3][0];
  float S2 = ws[0][1]+ws[1][1]+ws[2][1]+ws[3][1];
  float mean = S1 / 5376.0f;
  float var  = S2 / 5376.0f - mean*mean;
  float al = S[S_AG] * rsqrtf(var + 1e-5f);
  float bb = S[S_AB2];
  float cw = S[S_ACW], cb2 = S[S_ACB];
  int b = tid;
  float v[DV]; float mx = -1e30f;
  for (int d = 0; d < DV; d++){
    float a = att[b*DV + d];
    a = gelu_f(al*(a - mean) + bb);
    a = a*cw + cb2;
    v[d] = a; mx = fmaxf(mx, a);
  }
  float ss = 0.f;
  for (int d = 0; d < DV; d++){ v[d] = expf(v[d] - mx); ss += v[d]; }
  float inv = 1.0f / ss;
  for (int d = 0; d < DV; d++) att1[b*DV + d] = v[d] * inv;
}

// ---------------- build BcatT (256x512): rows 0..95 Wm1^T, 128..223 M^T, rest 0 ----------------
__global__ __launch_bounds__(256) void k_bcat(const float* __restrict__ Wm1, const float* __restrict__ M,
                                              float* __restrict__ BcatT){
  int i = blockIdx.x*256 + threadIdx.x;   // 131072
  int c = i >> 9, m = i & 511;
  float v = 0.f;
  if (c < 96) v = Wm1[m*96 + c];
  else if (c >= 128 && c < 224) v = M[m*96 + (c - 128)];
  BcatT[i] = v;
}

// ---------------- out = Zres + c + gelu(H + bm1) @ Wm2 + bm2, 16 rows/block ----------------
__global__ __launch_bounds__(256) void k_out(const float* __restrict__ Hcat, const float* __restrict__ c,
    const float* __restrict__ S, void* __restrict__ outv, const int* __restrict__ flag){
  const float* bm1 = S + S_BM1;
  const float* Wm2 = S + S_WM2;
  const float* bm2 = S + S_BM2;
  __shared__ float W2s[96*96];
  __shared__ float Hs[16][100];
  int blk = blockIdx.x, tid = threadIdx.x;
  int r0 = blk*16;
  for (int i = tid; i < 96*96; i += 256) W2s[i] = Wm2[i];
  for (int i = tid; i < 16*96; i += 256){
    int rr = i / 96, col = i - rr*96;
    Hs[rr][col] = gelu_f(Hcat[(size_t)(r0+rr)*256 + col] + bm1[col]);
  }
  __syncthreads();
  int rr = tid >> 4, c0 = (tid & 15)*6;
  float acc[6] = {};
  for (int k = 0; k < 96; k++){
    float h = Hs[rr][k];
    #pragma unroll
    for (int j = 0; j < 6; j++) acc[j] += h * W2s[k*96 + c0 + j];
  }
  int r = r0 + rr;
  int b = r / DV, d = r - b*DV;
  int mode = *flag;
  #pragma unroll
  for (int j = 0; j < 6; j++){
    int p = c0 + j;
    float val = Hcat[(size_t)r*256 + 128 + p] + c[p] + acc[j] + bm2[p];
    size_t oi = ((size_t)b*96 + p)*DV + d;
    if (mode) ((float*)outv)[oi] = val;
    else ((__hip_bfloat16*)outv)[oi] = __float2bfloat16(val);
  }
}

extern "C" void kernel_launch(void* const* d_in, const int* in_sizes, int n_in,
                              void* d_out, int out_size, void* d_ws, size_t ws_size,
                              hipStream_t stream) {
  float* w = (float*)d_ws;
  float* xt   = w + OFF_XT;
  float* zA   = w + OFF_ZA;
  float* z1   = w + OFF_Z1;
  float* zcp  = w + OFF_ZCP;
  float* D2   = w + OFF_D2;
  float* D3   = w + OFF_D3;
  float* Mb   = w + OFF_M;
  float* Tn   = w + OFF_TN;
  float* tb   = w + OFF_TB;
  float* cb   = w + OFF_C;
  float* en   = w + OFF_EN;
  float* nrm  = w + OFF_NORM;
  float* att  = w + OFF_ATT;
  float* att1 = w + OFF_ATT1;
  float* dvec = w + OFF_ATT1;     // alias: dvec dead before att1 is written
  float* stat = w + OFF_STAT;
  float* abd  = w + OFF_ABD;
  float* abp  = w + OFF_ABP;
  float* abdep= w + OFF_ABDEP;
  int*   flag = (int*)(w + OFF_FLAG);
  float* S    = w + OFF_STG;
  float* Hcat = zA;               // 5376x256, alias (zA dead after z2f)
  float* BcatT= zA + 1500000;     // 256x512, alias

  Ptrs ptrs;
  for (int i = 0; i < 30; i++) ptrs.p[i] = d_in[i];

  k_init<<<193, 256, 0, stream>>>((const unsigned*)d_in[13], stat, cb, Mb, flag);
  k_stage<<<3338, 256, 0, stream>>>(ptrs, S, flag);
  k_transpose<<<B_, 256, 0, stream>>>(d_in[0], xt, flag);
  k_dctmats<<<1024, 256, 0, stream>>>(D2, D3);
  k_dvec<<<2, 256, 0, stream>>>(S, dvec);
  k_foldM<<<dim3(192, 8), 256, 0, stream>>>(S, Mb);
  k_foldC<<<128, 256, 0, stream>>>(S, cb);
  k_foldTn<<<32, 256, 0, stream>>>(S, Tn, tb);

  k_gemm<0><<<dim3(8,84), 256, 0, stream>>>(xt, nullptr, D2, zA, nullptr, nullptr, nullptr, nullptr, 512);
  k_energy<<<NROW/4, 256, 0, stream>>>(zA, en);
  k_med<<<1, 256, 0, stream>>>(en, nrm);
  k_rank<<<336, 256, 0, stream>>>(nrm, S+S_THR, stat);
  k_maskgelu<<<NROW, 256, 0, stream>>>(zA, nrm, stat, S+S_THR, S+S_WDCT, S+S_BDCT, stat + 0);
  k_bnfin<<<1, 64, 0, stream>>>(stat + 0, S+S_GD, S+S_BDN, DV, 131072.0f, abd);
  k_gemm<1><<<dim3(8,84), 256, 0, stream>>>(zA, nullptr, D3, z1, abd, xt, S+S_WDCT, S+S_BDCT, 512);

  k_patch<<<NROW/8, 256, 0, stream>>>(xt, Tn, tb, zA, stat + 42);
  k_bnfin<<<1, 64, 0, stream>>>(stat + 42, S+S_GP, S+S_BP, NP, 86016.0f, abp);
  k_z2<<<NROW/8, 256, 0, stream>>>(zA, zcp, abp, S+S_WDC1, S+S_BDC1, stat + 106);
  k_bnfin<<<1, 64, 0, stream>>>(stat + 106, S+S_GDEP, S+S_BDEP, NP, 86016.0f, abdep);
  k_z2f<<<NROW*2, 256, 0, stream>>>(zcp, zA, abdep);

  k_att<<<NROW/4, 256, 0, stream>>>(z1, zcp, dvec, att);
  k_attfin<<<1, 256, 0, stream>>>(att, S, att1);

  k_bcat<<<512, 256, 0, stream>>>(S+S_WM1, Mb, BcatT);
  k_gemm<3><<<dim3(4,84), 256, 0, stream>>>(z1, zcp, BcatT, Hcat, att1, xt, nullptr, nullptr, 256);
  k_out<<<NROW/16, 256, 0, stream>>>(Hcat, cb, S, d_out, flag);
}